// Round 2
// baseline (417.050 us; speedup 1.0000x reference)
//
#include <hip/hip_runtime.h>

// ---------- common types ----------
typedef float  f32x4  __attribute__((ext_vector_type(4)));
typedef short  bf16x8 __attribute__((ext_vector_type(8)));

#define MFMA16(a, b, c) __builtin_amdgcn_mfma_f32_16x16x32_bf16((a), (b), (c), 0, 0, 0)

__device__ __forceinline__ short f2bf(float f) {
    union { float f; unsigned u; } a; a.f = f;
    unsigned r = a.u + 0x7fffu + ((a.u >> 16) & 1u);  // RNE
    return (short)(r >> 16);
}
__device__ __forceinline__ float bf2f(unsigned short u) {
    union { unsigned u; float f; } a; a.u = ((unsigned)u) << 16; return a.f;
}

// sizes
#define Bb   8
#define Nn   1024
#define DIM  768
#define HH   12
#define HD   64
#define INNER 768
#define SCALE 0.125f
// SCALE * log2(e): exp(s*SCALE) == exp2(s*SCL2E), one v_mul + v_exp_f32
#define SCL2E 0.18033688011112042f

// ---------- prep kernels ----------
__global__ void cast_to_bf16(const float* __restrict__ in, short* __restrict__ out, int n4) {
    int i = blockIdx.x * 256 + threadIdx.x;
    if (i >= n4) return;
    float4 f = reinterpret_cast<const float4*>(in)[i];
    unsigned lo = (unsigned)(unsigned short)f2bf(f.x) | ((unsigned)(unsigned short)f2bf(f.y) << 16);
    unsigned hi = (unsigned)(unsigned short)f2bf(f.z) | ((unsigned)(unsigned short)f2bf(f.w) << 16);
    reinterpret_cast<uint2*>(out)[i] = make_uint2(lo, hi);
}

// wt[c][k] = w[k][c]; w is [rows=K][cols], wt is [cols][K]
__global__ void transpose_cast(const float* __restrict__ w, short* __restrict__ wt,
                               int rows, int cols) {
    int idx = blockIdx.x * 256 + threadIdx.x;
    if (idx >= rows * cols) return;
    int c = idx / rows;
    int k = idx - c * rows;
    wt[idx] = f2bf(w[k * cols + c]);
}

// ---------- GEMM: C[M,N] = A[M,K] @ Bt[N,K]^T ----------
template <int MODE>
__global__ __launch_bounds__(256, 2)
void gemm128(const short* __restrict__ A, const short* __restrict__ Bt, int K,
             short* __restrict__ qb, short* __restrict__ kb, short* __restrict__ vtb,
             float* __restrict__ outp, const float* __restrict__ bias) {
    __shared__ __align__(16) short As[128 * 40];
    __shared__ __align__(16) short Bs[128 * 40];

    const int tid  = threadIdx.x;
    const int lane = tid & 63, wv = tid >> 6;
    const int wrow = wv >> 1, wcol = wv & 1;
    const int quad = lane >> 4, l16 = lane & 15;
    const int m0 = blockIdx.y * 128, n0 = blockIdx.x * 128;

    const int srow = tid >> 1;
    const int soff = (tid & 1) * 16;

    f32x4 acc[4][4];
#pragma unroll
    for (int i = 0; i < 4; i++)
#pragma unroll
        for (int j = 0; j < 4; j++) acc[i][j] = (f32x4){0.f, 0.f, 0.f, 0.f};

    for (int kc = 0; kc < K; kc += 32) {
        const uint4 a0 = *reinterpret_cast<const uint4*>(A + (size_t)(m0 + srow) * K + kc + soff);
        const uint4 a1 = *reinterpret_cast<const uint4*>(A + (size_t)(m0 + srow) * K + kc + soff + 8);
        const uint4 b0 = *reinterpret_cast<const uint4*>(Bt + (size_t)(n0 + srow) * K + kc + soff);
        const uint4 b1 = *reinterpret_cast<const uint4*>(Bt + (size_t)(n0 + srow) * K + kc + soff + 8);
        __syncthreads();
        *reinterpret_cast<uint4*>(&As[srow * 40 + soff])     = a0;
        *reinterpret_cast<uint4*>(&As[srow * 40 + soff + 8]) = a1;
        *reinterpret_cast<uint4*>(&Bs[srow * 40 + soff])     = b0;
        *reinterpret_cast<uint4*>(&Bs[srow * 40 + soff + 8]) = b1;
        __syncthreads();

        bf16x8 af[4], bfr[4];
#pragma unroll
        for (int t = 0; t < 4; t++)
            af[t] = *reinterpret_cast<bf16x8*>(&As[(wrow * 64 + t * 16 + l16) * 40 + quad * 8]);
#pragma unroll
        for (int t = 0; t < 4; t++)
            bfr[t] = *reinterpret_cast<bf16x8*>(&Bs[(wcol * 64 + t * 16 + l16) * 40 + quad * 8]);
#pragma unroll
        for (int rt = 0; rt < 4; rt++)
#pragma unroll
            for (int ct = 0; ct < 4; ct++)
                acc[rt][ct] = MFMA16(af[rt], bfr[ct], acc[rt][ct]);
    }

    // epilogue: C/D layout col=lane&15, row=quad*4+reg
#pragma unroll
    for (int rt = 0; rt < 4; rt++) {
#pragma unroll
        for (int ct = 0; ct < 4; ct++) {
            const int c = n0 + wcol * 64 + ct * 16 + l16;
#pragma unroll
            for (int reg = 0; reg < 4; reg++) {
                const int r = m0 + wrow * 64 + rt * 16 + quad * 4 + reg;
                const float v = acc[rt][ct][reg];
                if (MODE == 0) {
                    const int b = r >> 10, n = r & 1023;
                    const int which = (c >= 1536) ? 2 : (c >= 768 ? 1 : 0);
                    const int cc = c - which * 768;
                    const int h = cc >> 6, d = cc & 63;
                    const int bh = b * HH + h;
                    const short bv = f2bf(v);
                    if (which == 0)      qb[(bh << 16) + (n << 6) + d] = bv;
                    else if (which == 1) kb[(bh << 16) + (n << 6) + d] = bv;
                    else                 vtb[(bh << 16) + (d << 10) + n] = bv;
                } else {
                    outp[(size_t)r * 768 + c] = v + bias[c];
                }
            }
        }
    }
}

// ---------- attention pass 1 v4: no-LDS, no-barrier tiled denominator ----------
// Block = (b, n128, m128): 512 blocks x 512 threads = 2 blocks/CU = 16 waves/CU.
// ZERO LDS, ZERO barriers: each wave loads its MFMA fragments directly from
// global. Rationale: the old stage->barrier->ds_read structure kept all 16
// waves/CU in lockstep (LDS burst while MFMA idle, then compute while LDS
// idle) and exposed a full vmcnt+barrier drain 12x per block; measured 72us
// vs ~25us cycle budget. Q/K slice for one b is 3 MB and the b = bid&7
// swizzle pins it in that XCD's 4 MB L2, so fragment re-reads are L1/L2
// hits. Unsynchronized waves drift out of phase -> L2 latency hides under
// other waves' MFMA/exp.
__global__ __launch_bounds__(512, 4)
void attn_den4(const short* __restrict__ qb, const short* __restrict__ kb,
               short* __restrict__ invp) {
    const int tid = threadIdx.x, lane = tid & 63, wv = tid >> 6;  // wv 0..7
    const int wrow = wv >> 2, wcol = wv & 3;                      // 2 x 4
    const int quad = lane >> 4, l16 = lane & 15;
    const int bid = blockIdx.x;
    const int b = bid & 7;
    const int nmt = bid >> 3;            // 0..63
    const int n0 = (nmt >> 3) << 7;      // n128 base
    const int m0 = (nmt & 7) << 7;       // m128 base

    f32x4 den[4][2];
#pragma unroll
    for (int i = 0; i < 4; i++)
#pragma unroll
        for (int j = 0; j < 2; j++) den[i][j] = (f32x4){0.f, 0.f, 0.f, 0.f};
    const f32x4 z = (f32x4){0.f, 0.f, 0.f, 0.f};

    // per-lane fragment base addresses (head 0)
    const short* qbase = qb + ((b * HH) << 16) + ((n0 + wrow * 64 + l16) << 6) + quad * 8;
    const short* kbase = kb + ((b * HH) << 16) + ((m0 + wcol * 32 + l16) << 6) + quad * 8;

#pragma unroll
    for (int h = 0; h < HH; h++) {
        const short* qp = qbase + (h << 16);
        const short* kp = kbase + (h << 16);
        bf16x8 aq[4][2], bk[2][2];
#pragma unroll
        for (int t = 0; t < 4; t++) {
            aq[t][0] = *reinterpret_cast<const bf16x8*>(qp + (t << 10));       // +t*16 rows
            aq[t][1] = *reinterpret_cast<const bf16x8*>(qp + (t << 10) + 32);  // d 32..63
        }
#pragma unroll
        for (int t = 0; t < 2; t++) {
            bk[t][0] = *reinterpret_cast<const bf16x8*>(kp + (t << 10));
            bk[t][1] = *reinterpret_cast<const bf16x8*>(kp + (t << 10) + 32);
        }
#pragma unroll
        for (int nt = 0; nt < 4; nt++)
#pragma unroll
            for (int mt = 0; mt < 2; mt++) {
                f32x4 s = MFMA16(aq[nt][0], bk[mt][0], z);
                s = MFMA16(aq[nt][1], bk[mt][1], s);
#pragma unroll
                for (int r = 0; r < 4; r++)
                    den[nt][mt][r] += __builtin_amdgcn_exp2f(s[r] * SCL2E);
            }
    }

    // write inv_den in raw (tile, lane, reg) C-layout (same as pass 2 reads)
#pragma unroll
    for (int nt = 0; nt < 4; nt++)
#pragma unroll
        for (int mt = 0; mt < 2; mt++) {
            const int ntg = (n0 >> 4) + wrow * 4 + nt;
            const int mtg = (m0 >> 4) + wcol * 2 + mt;
            ushort4 o;
            o.x = (unsigned short)f2bf(1.0f / den[nt][mt][0]);
            o.y = (unsigned short)f2bf(1.0f / den[nt][mt][1]);
            o.z = (unsigned short)f2bf(1.0f / den[nt][mt][2]);
            o.w = (unsigned short)f2bf(1.0f / den[nt][mt][3]);
            *reinterpret_cast<ushort4*>(&invp[(((b * 64 + ntg) * 64 + mtg) * 64 + lane) * 4]) = o;
        }
}

// ---------- attention pass 2 v2: per-head recompute-S + PV ----------
// Block = (b, h, n128): 768 blocks (3/CU), 4 waves, wave = 32 n-rows.
// K/V double-buffered in LDS -> ONE barrier per m32-iter. P transposed
// through wave-private LDS stash (intra-wave, no barrier).
__global__ __launch_bounds__(256, 4)
void attn_pv2(const short* __restrict__ qb, const short* __restrict__ kb,
              const short* __restrict__ vtb, const short* __restrict__ invp,
              short* __restrict__ attn_out) {
    __shared__ __align__(16) short Ks[2][32 * 72];   // [m][d]
    __shared__ __align__(16) short Vs[2][64 * 40];   // [d][m]
    __shared__ __align__(16) short Ps[4][32 * 40];   // per-wave [n][m]

    const int tid = threadIdx.x, lane = tid & 63, wv = tid >> 6;
    const int quad = lane >> 4, l16 = lane & 15;
    const int bid = blockIdx.x;
    const int b = bid & 7;
    const int r = bid >> 3;              // 0..95
    const int n4 = r / 12;               // 0..7 (n128 tile)
    const int h = r - n4 * 12;
    const int nb = n4 << 7;
    const int bh = b * HH + h;

    // Q A-frags for 2 n16-tiles
    bf16x8 aq[2][2];
#pragma unroll
    for (int nt = 0; nt < 2; nt++) {
        const short* qp = qb + (bh << 16) + ((nb + wv * 32 + nt * 16 + l16) << 6) + quad * 8;
        aq[nt][0] = *reinterpret_cast<const bf16x8*>(qp);
        aq[nt][1] = *reinterpret_cast<const bf16x8*>(qp + 32);
    }

    const f32x4 z = (f32x4){0.f, 0.f, 0.f, 0.f};
    f32x4 O[2][4];
#pragma unroll
    for (int nt = 0; nt < 2; nt++)
#pragma unroll
        for (int d = 0; d < 4; d++) O[nt][d] = z;

    const int krow = tid >> 3, koff = (tid & 7) * 8;   // K: 32 rows x 128B
    const int vrow = tid >> 2, voff = (tid & 3) * 8;   // V: 64 rows x 64B

    // preload tile 0
    uint4 kreg = *reinterpret_cast<const uint4*>(kb + (bh << 16) + (krow << 6) + koff);
    uint4 vreg = *reinterpret_cast<const uint4*>(vtb + (bh << 16) + (vrow << 10) + voff);

    for (int it = 0; it < 32; it++) {
        const int p = it & 1;
        *reinterpret_cast<uint4*>(&Ks[p][krow * 72 + koff]) = kreg;
        *reinterpret_cast<uint4*>(&Vs[p][vrow * 40 + voff]) = vreg;
        __syncthreads();
        if (it < 31) {
            const int m1 = (it + 1) << 5;
            kreg = *reinterpret_cast<const uint4*>(kb + (bh << 16) + ((m1 + krow) << 6) + koff);
            vreg = *reinterpret_cast<const uint4*>(vtb + (bh << 16) + (vrow << 10) + m1 + voff);
        }
        const int m0 = it << 5;

        // S + P-stash for two m16-halves x two n-tiles
#pragma unroll
        for (int mh = 0; mh < 2; mh++) {
            const bf16x8 k0 = *reinterpret_cast<bf16x8*>(&Ks[p][(mh * 16 + l16) * 72 + quad * 8]);
            const bf16x8 k1 = *reinterpret_cast<bf16x8*>(&Ks[p][(mh * 16 + l16) * 72 + quad * 8 + 32]);
            const int mt = (m0 >> 4) + mh;
#pragma unroll
            for (int nt = 0; nt < 2; nt++) {
                f32x4 s = MFMA16(aq[nt][0], k0, z);
                s = MFMA16(aq[nt][1], k1, s);
                const int ntg = (nb >> 4) + wv * 2 + nt;
                const ushort4 iv = *reinterpret_cast<const ushort4*>(
                    &invp[(((b * 64 + ntg) * 64 + mt) * 64 + lane) * 4]);
                Ps[wv][(nt * 16 + quad * 4 + 0) * 40 + mh * 16 + l16] = f2bf(__expf(s[0] * SCALE) * bf2f(iv.x));
                Ps[wv][(nt * 16 + quad * 4 + 1) * 40 + mh * 16 + l16] = f2bf(__expf(s[1] * SCALE) * bf2f(iv.y));
                Ps[wv][(nt * 16 + quad * 4 + 2) * 40 + mh * 16 + l16] = f2bf(__expf(s[2] * SCALE) * bf2f(iv.z));
                Ps[wv][(nt * 16 + quad * 4 + 3) * 40 + mh * 16 + l16] = f2bf(__expf(s[3] * SCALE) * bf2f(iv.w));
            }
        }
        __threadfence_block();  // intra-wave cross-lane RAW on Ps

        // PV
        bf16x8 pa[2];
#pragma unroll
        for (int nt = 0; nt < 2; nt++)
            pa[nt] = *reinterpret_cast<bf16x8*>(&Ps[wv][(nt * 16 + l16) * 40 + quad * 8]);
#pragma unroll
        for (int dch = 0; dch < 4; dch++) {
            const bf16x8 vf = *reinterpret_cast<bf16x8*>(&Vs[p][(dch * 16 + l16) * 40 + quad * 8]);
#pragma unroll
            for (int nt = 0; nt < 2; nt++)
                O[nt][dch] = MFMA16(pa[nt], vf, O[nt][dch]);
        }
    }

    // epilogue
#pragma unroll
    for (int nt = 0; nt < 2; nt++)
#pragma unroll
        for (int dch = 0; dch < 4; dch++) {
            const int col = h * 64 + dch * 16 + l16;
#pragma unroll
            for (int reg = 0; reg < 4; reg++) {
                const int n = nb + wv * 32 + nt * 16 + quad * 4 + reg;
                attn_out[(size_t)((b << 10) + n) * 768 + col] = f2bf(O[nt][dch][reg]);
            }
        }
}

// ---------- launch ----------
extern "C" void kernel_launch(void* const* d_in, const int* in_sizes, int n_in,
                              void* d_out, int out_size, void* d_ws, size_t ws_size,
                              hipStream_t stream) {
    const float* x     = (const float*)d_in[0];
    const float* w_qkv = (const float*)d_in[1];
    const float* w_out = (const float*)d_in[2];
    const float* b_out = (const float*)d_in[3];
    float* out = (float*)d_out;

    short* xb   = (short*)d_ws;                 // [8192][768]
    short* wT1  = xb  + 8192 * 768;             // [2304][768]
    short* wT2  = wT1 + 2304 * 768;             // [768][768]
    short* qb   = wT2 + 768 * 768;              // [b][h][n][d]
    short* kb   = qb  + 96 * 65536;
    short* vtb  = kb  + 96 * 65536;             // [b][h][d][n]
    short* attn = vtb + 96 * 65536;             // [8192][768]
    short* invp = attn + 8192 * 768;            // [b][nt][mt][lane][4]

    cast_to_bf16<<<6144, 256, 0, stream>>>(x, xb, (8192 * 768) / 4);
    transpose_cast<<<(2304 * 768) / 256, 256, 0, stream>>>(w_qkv, wT1, 768, 2304);
    transpose_cast<<<(768 * 768) / 256, 256, 0, stream>>>(w_out, wT2, 768, 768);

    gemm128<0><<<dim3(2304 / 128, 8192 / 128), 256, 0, stream>>>(
        xb, wT1, 768, qb, kb, vtb, nullptr, nullptr);

    attn_den4<<<512, 512, 0, stream>>>(qb, kb, invp);
    attn_pv2<<<768, 256, 0, stream>>>(qb, kb, vtb, invp, attn);

    gemm128<1><<<dim3(768 / 128, 8192 / 128), 256, 0, stream>>>(
        attn, wT2, 768, nullptr, nullptr, nullptr, out, b_out);
}

// Round 3
// 257.505 us; speedup vs baseline: 1.6196x; 1.6196x over previous
//
#include <hip/hip_runtime.h>

// ---------- common types ----------
typedef float  f32x4  __attribute__((ext_vector_type(4)));
typedef short  bf16x8 __attribute__((ext_vector_type(8)));

#define MFMA16(a, b, c) __builtin_amdgcn_mfma_f32_16x16x32_bf16((a), (b), (c), 0, 0, 0)

// global -> LDS direct DMA, 16B per lane. LDS dest is wave-uniform base +
// lane*16 (linear); global src is per-lane.
#define GLL16(g, l) __builtin_amdgcn_global_load_lds(                      \
    (const __attribute__((address_space(1))) void*)(g),                    \
    (__attribute__((address_space(3))) void*)(l), 16, 0, 0)

__device__ __forceinline__ short f2bf(float f) {
    union { float f; unsigned u; } a; a.f = f;
    unsigned r = a.u + 0x7fffu + ((a.u >> 16) & 1u);  // RNE
    return (short)(r >> 16);
}
__device__ __forceinline__ float bf2f(unsigned short u) {
    union { unsigned u; float f; } a; a.u = ((unsigned)u) << 16; return a.f;
}

// sizes
#define Bb   8
#define Nn   1024
#define DIM  768
#define HH   12
#define HD   64
#define INNER 768
#define SCALE 0.125f
// SCALE * log2(e): exp(s*SCALE) == exp2(s*SCL2E)
#define SCL2E 0.18033688011112042f

// ---------- prep kernels ----------
__global__ void cast_to_bf16(const float* __restrict__ in, short* __restrict__ out, int n4) {
    int i = blockIdx.x * 256 + threadIdx.x;
    if (i >= n4) return;
    float4 f = reinterpret_cast<const float4*>(in)[i];
    unsigned lo = (unsigned)(unsigned short)f2bf(f.x) | ((unsigned)(unsigned short)f2bf(f.y) << 16);
    unsigned hi = (unsigned)(unsigned short)f2bf(f.z) | ((unsigned)(unsigned short)f2bf(f.w) << 16);
    reinterpret_cast<uint2*>(out)[i] = make_uint2(lo, hi);
}

// wt[c][k] = w[k][c]; w is [rows=K][cols], wt is [cols][K]
__global__ void transpose_cast(const float* __restrict__ w, short* __restrict__ wt,
                               int rows, int cols) {
    int idx = blockIdx.x * 256 + threadIdx.x;
    if (idx >= rows * cols) return;
    int c = idx / rows;
    int k = idx - c * rows;
    wt[idx] = f2bf(w[k * cols + c]);
}

// ---------- GEMM: C[M,N] = A[M,K] @ Bt[N,K]^T ----------
template <int MODE>
__global__ __launch_bounds__(256, 2)
void gemm128(const short* __restrict__ A, const short* __restrict__ Bt, int K,
             short* __restrict__ qb, short* __restrict__ kb, short* __restrict__ vtb,
             float* __restrict__ outp, const float* __restrict__ bias) {
    __shared__ __align__(16) short As[128 * 40];
    __shared__ __align__(16) short Bs[128 * 40];

    const int tid  = threadIdx.x;
    const int lane = tid & 63, wv = tid >> 6;
    const int wrow = wv >> 1, wcol = wv & 1;
    const int quad = lane >> 4, l16 = lane & 15;
    const int m0 = blockIdx.y * 128, n0 = blockIdx.x * 128;

    const int srow = tid >> 1;
    const int soff = (tid & 1) * 16;

    f32x4 acc[4][4];
#pragma unroll
    for (int i = 0; i < 4; i++)
#pragma unroll
        for (int j = 0; j < 4; j++) acc[i][j] = (f32x4){0.f, 0.f, 0.f, 0.f};

    for (int kc = 0; kc < K; kc += 32) {
        const uint4 a0 = *reinterpret_cast<const uint4*>(A + (size_t)(m0 + srow) * K + kc + soff);
        const uint4 a1 = *reinterpret_cast<const uint4*>(A + (size_t)(m0 + srow) * K + kc + soff + 8);
        const uint4 b0 = *reinterpret_cast<const uint4*>(Bt + (size_t)(n0 + srow) * K + kc + soff);
        const uint4 b1 = *reinterpret_cast<const uint4*>(Bt + (size_t)(n0 + srow) * K + kc + soff + 8);
        __syncthreads();
        *reinterpret_cast<uint4*>(&As[srow * 40 + soff])     = a0;
        *reinterpret_cast<uint4*>(&As[srow * 40 + soff + 8]) = a1;
        *reinterpret_cast<uint4*>(&Bs[srow * 40 + soff])     = b0;
        *reinterpret_cast<uint4*>(&Bs[srow * 40 + soff + 8]) = b1;
        __syncthreads();

        bf16x8 af[4], bfr[4];
#pragma unroll
        for (int t = 0; t < 4; t++)
            af[t] = *reinterpret_cast<bf16x8*>(&As[(wrow * 64 + t * 16 + l16) * 40 + quad * 8]);
#pragma unroll
        for (int t = 0; t < 4; t++)
            bfr[t] = *reinterpret_cast<bf16x8*>(&Bs[(wcol * 64 + t * 16 + l16) * 40 + quad * 8]);
#pragma unroll
        for (int rt = 0; rt < 4; rt++)
#pragma unroll
            for (int ct = 0; ct < 4; ct++)
                acc[rt][ct] = MFMA16(af[rt], bfr[ct], acc[rt][ct]);
    }

    // epilogue: C/D layout col=lane&15, row=quad*4+reg
#pragma unroll
    for (int rt = 0; rt < 4; rt++) {
#pragma unroll
        for (int ct = 0; ct < 4; ct++) {
            const int c = n0 + wcol * 64 + ct * 16 + l16;
#pragma unroll
            for (int reg = 0; reg < 4; reg++) {
                const int r = m0 + wrow * 64 + rt * 16 + quad * 4 + reg;
                const float v = acc[rt][ct][reg];
                if (MODE == 0) {
                    const int b = r >> 10, n = r & 1023;
                    const int which = (c >= 1536) ? 2 : (c >= 768 ? 1 : 0);
                    const int cc = c - which * 768;
                    const int h = cc >> 6, d = cc & 63;
                    const int bh = b * HH + h;
                    const short bv = f2bf(v);
                    if (which == 0)      qb[(bh << 16) + (n << 6) + d] = bv;
                    else if (which == 1) kb[(bh << 16) + (n << 6) + d] = bv;
                    else                 vtb[(bh << 16) + (d << 10) + n] = bv;
                } else {
                    outp[(size_t)r * 768 + c] = v + bias[c];
                }
            }
        }
    }
}

// ---------- attention pass 1 v5: gll + double-buffer + XOR swizzle ----------
// Block = (b, n128, m128): 512 blocks x 512 threads, 2 blocks/CU (64 KB LDS).
// Staging via global_load_lds (no VGPR round-trip, no ds_write cost),
// DOUBLE-buffered: head h+1's DMA is issued right after the single per-head
// barrier and lands during head h's full compute phase (m97 pipeline).
// Rows are 128 B unpadded (gll writes linearly) -> XOR-swizzle 16B units:
// global unit g stored at LDS unit g^(row&7); pre-swizzled on the global
// source side, un-swizzled on the ds_read side (both-sides-or-neither).
// b = bid&7 pins each batch's 3 MB Q+K slice in one XCD's L2.
__global__ __launch_bounds__(512, 4)
void attn_den5(const short* __restrict__ qb, const short* __restrict__ kb,
               short* __restrict__ invp) {
    __shared__ __align__(16) short Qs[2][128 * 64];
    __shared__ __align__(16) short Ks[2][128 * 64];

    const int tid = threadIdx.x, lane = tid & 63, wv = tid >> 6;  // wv 0..7
    const int wrow = wv >> 2, wcol = wv & 3;                      // 2 x 4
    const int quad = lane >> 4, l16 = lane & 15;
    const int bid = blockIdx.x;
    const int b = bid & 7;
    const int nmt = bid >> 3;            // 0..63
    const int n0 = (nmt >> 3) << 7;      // n128 base
    const int m0 = (nmt & 7) << 7;       // m128 base

    // ---- stage addressing (per-lane global, wave-uniform LDS) ----
    // wave covers 8 rows x 128B per call; row = it*64 + wv*8 + (lane>>3),
    // LDS unit = lane&7 (linear), so fetch global unit (lane&7)^(row&7).
    const int r8 = lane >> 3;                 // 0..7, == row&7
    const int gu = (lane & 7) ^ r8;           // pre-swizzled global unit
    const int qo0 = (n0 + wv * 8 + r8) * 64 + gu * 8;   // shorts
    const int qo1 = qo0 + 64 * 64;                      // +64 rows
    const int ko0 = (m0 + wv * 8 + r8) * 64 + gu * 8;
    const int ko1 = ko0 + 64 * 64;
    const int lc0 = wv * 512;                 // wave LDS chunk, it=0 (shorts)
    const int lc1 = 4096 + wv * 512;          // it=1

    f32x4 den[4][2];
#pragma unroll
    for (int i = 0; i < 4; i++)
#pragma unroll
        for (int j = 0; j < 2; j++) den[i][j] = (f32x4){0.f, 0.f, 0.f, 0.f};
    const f32x4 z = (f32x4){0.f, 0.f, 0.f, 0.f};

    // prologue: stage head 0 into buffer 0
    {
        const short* qh = qb + ((size_t)(b * HH) << 16);
        const short* kh = kb + ((size_t)(b * HH) << 16);
        GLL16(qh + qo0, &Qs[0][lc0]);
        GLL16(qh + qo1, &Qs[0][lc1]);
        GLL16(kh + ko0, &Ks[0][lc0]);
        GLL16(kh + ko1, &Ks[0][lc1]);
    }

    for (int h = 0; h < HH; h++) {
        asm volatile("s_waitcnt vmcnt(0)" ::: "memory");  // this head's DMA landed
        __syncthreads();                                  // all waves see it
        if (h < HH - 1) {  // issue next head's DMA into the other buffer
            const int pn = (h + 1) & 1;
            const short* qh = qb + ((size_t)(b * HH + h + 1) << 16);
            const short* kh = kb + ((size_t)(b * HH + h + 1) << 16);
            GLL16(qh + qo0, &Qs[pn][lc0]);
            GLL16(qh + qo1, &Qs[pn][lc1]);
            GLL16(kh + ko0, &Ks[pn][lc0]);
            GLL16(kh + ko1, &Ks[pn][lc1]);
        }
        const int pb = h & 1;
        const int sw0 = (quad ^ (l16 & 7)) * 8;   // swizzled unit, half 0 (shorts)

        bf16x8 aq[4][2], bk[2][2];
#pragma unroll
        for (int t = 0; t < 4; t++) {
            const int row = wrow * 64 + t * 16 + l16;
            aq[t][0] = *reinterpret_cast<bf16x8*>(&Qs[pb][row * 64 + sw0]);
            aq[t][1] = *reinterpret_cast<bf16x8*>(&Qs[pb][row * 64 + (sw0 ^ 32)]);
        }
#pragma unroll
        for (int t = 0; t < 2; t++) {
            const int row = wcol * 32 + t * 16 + l16;
            bk[t][0] = *reinterpret_cast<bf16x8*>(&Ks[pb][row * 64 + sw0]);
            bk[t][1] = *reinterpret_cast<bf16x8*>(&Ks[pb][row * 64 + (sw0 ^ 32)]);
        }
#pragma unroll
        for (int nt = 0; nt < 4; nt++)
#pragma unroll
            for (int mt = 0; mt < 2; mt++) {
                f32x4 s = MFMA16(aq[nt][0], bk[mt][0], z);
                s = MFMA16(aq[nt][1], bk[mt][1], s);
#pragma unroll
                for (int r = 0; r < 4; r++)
                    den[nt][mt][r] += __builtin_amdgcn_exp2f(s[r] * SCL2E);
            }
    }

    // write inv_den in raw (tile, lane, reg) C-layout (same as pass 2 reads)
#pragma unroll
    for (int nt = 0; nt < 4; nt++)
#pragma unroll
        for (int mt = 0; mt < 2; mt++) {
            const int ntg = (n0 >> 4) + wrow * 4 + nt;
            const int mtg = (m0 >> 4) + wcol * 2 + mt;
            ushort4 o;
            o.x = (unsigned short)f2bf(1.0f / den[nt][mt][0]);
            o.y = (unsigned short)f2bf(1.0f / den[nt][mt][1]);
            o.z = (unsigned short)f2bf(1.0f / den[nt][mt][2]);
            o.w = (unsigned short)f2bf(1.0f / den[nt][mt][3]);
            *reinterpret_cast<ushort4*>(&invp[(((b * 64 + ntg) * 64 + mtg) * 64 + lane) * 4]) = o;
        }
}

// ---------- attention pass 2 v2: per-head recompute-S + PV ----------
// Block = (b, h, n128): 768 blocks (3/CU), 4 waves, wave = 32 n-rows.
// K/V double-buffered in LDS -> ONE barrier per m32-iter. P transposed
// through wave-private LDS stash (intra-wave, no barrier).
__global__ __launch_bounds__(256, 4)
void attn_pv2(const short* __restrict__ qb, const short* __restrict__ kb,
              const short* __restrict__ vtb, const short* __restrict__ invp,
              short* __restrict__ attn_out) {
    __shared__ __align__(16) short Ks[2][32 * 72];   // [m][d]
    __shared__ __align__(16) short Vs[2][64 * 40];   // [d][m]
    __shared__ __align__(16) short Ps[4][32 * 40];   // per-wave [n][m]

    const int tid = threadIdx.x, lane = tid & 63, wv = tid >> 6;
    const int quad = lane >> 4, l16 = lane & 15;
    const int bid = blockIdx.x;
    const int b = bid & 7;
    const int r = bid >> 3;              // 0..95
    const int n4 = r / 12;               // 0..7 (n128 tile)
    const int h = r - n4 * 12;
    const int nb = n4 << 7;
    const int bh = b * HH + h;

    // Q A-frags for 2 n16-tiles
    bf16x8 aq[2][2];
#pragma unroll
    for (int nt = 0; nt < 2; nt++) {
        const short* qp = qb + (bh << 16) + ((nb + wv * 32 + nt * 16 + l16) << 6) + quad * 8;
        aq[nt][0] = *reinterpret_cast<const bf16x8*>(qp);
        aq[nt][1] = *reinterpret_cast<const bf16x8*>(qp + 32);
    }

    const f32x4 z = (f32x4){0.f, 0.f, 0.f, 0.f};
    f32x4 O[2][4];
#pragma unroll
    for (int nt = 0; nt < 2; nt++)
#pragma unroll
        for (int d = 0; d < 4; d++) O[nt][d] = z;

    const int krow = tid >> 3, koff = (tid & 7) * 8;   // K: 32 rows x 128B
    const int vrow = tid >> 2, voff = (tid & 3) * 8;   // V: 64 rows x 64B

    // preload tile 0
    uint4 kreg = *reinterpret_cast<const uint4*>(kb + (bh << 16) + (krow << 6) + koff);
    uint4 vreg = *reinterpret_cast<const uint4*>(vtb + (bh << 16) + (vrow << 10) + voff);

    for (int it = 0; it < 32; it++) {
        const int p = it & 1;
        *reinterpret_cast<uint4*>(&Ks[p][krow * 72 + koff]) = kreg;
        *reinterpret_cast<uint4*>(&Vs[p][vrow * 40 + voff]) = vreg;
        __syncthreads();
        if (it < 31) {
            const int m1 = (it + 1) << 5;
            kreg = *reinterpret_cast<const uint4*>(kb + (bh << 16) + ((m1 + krow) << 6) + koff);
            vreg = *reinterpret_cast<const uint4*>(vtb + (bh << 16) + (vrow << 10) + m1 + voff);
        }
        const int m0 = it << 5;

        // S + P-stash for two m16-halves x two n-tiles
#pragma unroll
        for (int mh = 0; mh < 2; mh++) {
            const bf16x8 k0 = *reinterpret_cast<bf16x8*>(&Ks[p][(mh * 16 + l16) * 72 + quad * 8]);
            const bf16x8 k1 = *reinterpret_cast<bf16x8*>(&Ks[p][(mh * 16 + l16) * 72 + quad * 8 + 32]);
            const int mt = (m0 >> 4) + mh;
#pragma unroll
            for (int nt = 0; nt < 2; nt++) {
                f32x4 s = MFMA16(aq[nt][0], k0, z);
                s = MFMA16(aq[nt][1], k1, s);
                const int ntg = (nb >> 4) + wv * 2 + nt;
                const ushort4 iv = *reinterpret_cast<const ushort4*>(
                    &invp[(((b * 64 + ntg) * 64 + mt) * 64 + lane) * 4]);
                Ps[wv][(nt * 16 + quad * 4 + 0) * 40 + mh * 16 + l16] = f2bf(__expf(s[0] * SCALE) * bf2f(iv.x));
                Ps[wv][(nt * 16 + quad * 4 + 1) * 40 + mh * 16 + l16] = f2bf(__expf(s[1] * SCALE) * bf2f(iv.y));
                Ps[wv][(nt * 16 + quad * 4 + 2) * 40 + mh * 16 + l16] = f2bf(__expf(s[2] * SCALE) * bf2f(iv.z));
                Ps[wv][(nt * 16 + quad * 4 + 3) * 40 + mh * 16 + l16] = f2bf(__expf(s[3] * SCALE) * bf2f(iv.w));
            }
        }
        __threadfence_block();  // intra-wave cross-lane RAW on Ps

        // PV
        bf16x8 pa[2];
#pragma unroll
        for (int nt = 0; nt < 2; nt++)
            pa[nt] = *reinterpret_cast<bf16x8*>(&Ps[wv][(nt * 16 + l16) * 40 + quad * 8]);
#pragma unroll
        for (int dch = 0; dch < 4; dch++) {
            const bf16x8 vf = *reinterpret_cast<bf16x8*>(&Vs[p][(dch * 16 + l16) * 40 + quad * 8]);
#pragma unroll
            for (int nt = 0; nt < 2; nt++)
                O[nt][dch] = MFMA16(pa[nt], vf, O[nt][dch]);
        }
    }

    // epilogue
#pragma unroll
    for (int nt = 0; nt < 2; nt++)
#pragma unroll
        for (int dch = 0; dch < 4; dch++) {
            const int col = h * 64 + dch * 16 + l16;
#pragma unroll
            for (int reg = 0; reg < 4; reg++) {
                const int n = nb + wv * 32 + nt * 16 + quad * 4 + reg;
                attn_out[(size_t)((b << 10) + n) * 768 + col] = f2bf(O[nt][dch][reg]);
            }
        }
}

// ---------- launch ----------
extern "C" void kernel_launch(void* const* d_in, const int* in_sizes, int n_in,
                              void* d_out, int out_size, void* d_ws, size_t ws_size,
                              hipStream_t stream) {
    const float* x     = (const float*)d_in[0];
    const float* w_qkv = (const float*)d_in[1];
    const float* w_out = (const float*)d_in[2];
    const float* b_out = (const float*)d_in[3];
    float* out = (float*)d_out;

    short* xb   = (short*)d_ws;                 // [8192][768]
    short* wT1  = xb  + 8192 * 768;             // [2304][768]
    short* wT2  = wT1 + 2304 * 768;             // [768][768]
    short* qb   = wT2 + 768 * 768;              // [b][h][n][d]
    short* kb   = qb  + 96 * 65536;
    short* vtb  = kb  + 96 * 65536;             // [b][h][d][n]
    short* attn = vtb + 96 * 65536;             // [8192][768]
    short* invp = attn + 8192 * 768;            // [b][nt][mt][lane][4]

    cast_to_bf16<<<6144, 256, 0, stream>>>(x, xb, (8192 * 768) / 4);
    transpose_cast<<<(2304 * 768) / 256, 256, 0, stream>>>(w_qkv, wT1, 768, 2304);
    transpose_cast<<<(768 * 768) / 256, 256, 0, stream>>>(w_out, wT2, 768, 768);

    gemm128<0><<<dim3(2304 / 128, 8192 / 128), 256, 0, stream>>>(
        xb, wT1, 768, qb, kb, vtb, nullptr, nullptr);

    attn_den5<<<512, 512, 0, stream>>>(qb, kb, invp);
    attn_pv2<<<768, 256, 0, stream>>>(qb, kb, vtb, invp, attn);

    gemm128<1><<<dim3(768 / 128, 8192 / 128), 256, 0, stream>>>(
        attn, wT2, 768, nullptr, nullptr, nullptr, out, b_out);
}

// Round 4
// 257.427 us; speedup vs baseline: 1.6201x; 1.0003x over previous
//
#include <hip/hip_runtime.h>

// ---------- common types ----------
typedef float  f32x4  __attribute__((ext_vector_type(4)));
typedef short  bf16x8 __attribute__((ext_vector_type(8)));

#define MFMA16(a, b, c) __builtin_amdgcn_mfma_f32_16x16x32_bf16((a), (b), (c), 0, 0, 0)

// global -> LDS direct DMA, 16B per lane. LDS dest is wave-uniform base +
// lane*16 (linear); global src is per-lane.
#define GLL16(g, l) __builtin_amdgcn_global_load_lds(                      \
    (const __attribute__((address_space(1))) void*)(g),                    \
    (__attribute__((address_space(3))) void*)(l), 16, 0, 0)

__device__ __forceinline__ short f2bf(float f) {
    union { float f; unsigned u; } a; a.f = f;
    unsigned r = a.u + 0x7fffu + ((a.u >> 16) & 1u);  // RNE
    return (short)(r >> 16);
}
__device__ __forceinline__ float bf2f(unsigned short u) {
    union { unsigned u; float f; } a; a.u = ((unsigned)u) << 16; return a.f;
}

// sizes
#define Bb   8
#define Nn   1024
#define DIM  768
#define HH   12
#define HD   64
#define INNER 768
#define SCALE 0.125f
// SCALE * log2(e): exp(s*SCALE) == exp2(s*SCL2E)
#define SCL2E 0.18033688011112042f

// ---------- prep kernels ----------
__global__ void cast_to_bf16(const float* __restrict__ in, short* __restrict__ out, int n4) {
    int i = blockIdx.x * 256 + threadIdx.x;
    if (i >= n4) return;
    float4 f = reinterpret_cast<const float4*>(in)[i];
    unsigned lo = (unsigned)(unsigned short)f2bf(f.x) | ((unsigned)(unsigned short)f2bf(f.y) << 16);
    unsigned hi = (unsigned)(unsigned short)f2bf(f.z) | ((unsigned)(unsigned short)f2bf(f.w) << 16);
    reinterpret_cast<uint2*>(out)[i] = make_uint2(lo, hi);
}

// wt[c][k] = w[k][c]; w is [rows=K][cols], wt is [cols][K]
__global__ void transpose_cast(const float* __restrict__ w, short* __restrict__ wt,
                               int rows, int cols) {
    int idx = blockIdx.x * 256 + threadIdx.x;
    if (idx >= rows * cols) return;
    int c = idx / rows;
    int k = idx - c * rows;
    wt[idx] = f2bf(w[k * cols + c]);
}

// ---------- GEMM v3: gll staging + dbuf + XOR swizzle ----------
// C[M,N] = A[M,K] @ Bt[N,K]^T. 128x128 tile, BK=32, 4 waves (2x2, 64x64 each).
// Staging via global_load_lds (no VGPR round-trip), double-buffered LDS with
// ONE barrier per K-step (attn_den5-proven pattern: wait vmcnt(0) -> barrier
// -> issue next K-step's DMA -> compute).
// LDS rows are 64 B unpadded (gll writes linearly); 16B-unit XOR swizzle
// unit' = unit ^ ((row>>1)&3), applied on the global SOURCE side at stage
// and un-applied at ds_read (both-sides-or-neither). Read banks: 16 lanes
// map 2-per-(parity,unit) = 2-way = free.
template <int MODE>
__global__ __launch_bounds__(256, 4)
void gemm128(const short* __restrict__ A, const short* __restrict__ Bt, int K,
             short* __restrict__ qb, short* __restrict__ kb, short* __restrict__ vtb,
             float* __restrict__ outp, const float* __restrict__ bias) {
    __shared__ __align__(16) short As[2][128 * 32];
    __shared__ __align__(16) short Bs[2][128 * 32];

    const int tid  = threadIdx.x;
    const int lane = tid & 63, wv = tid >> 6;
    const int wrow = wv >> 1, wcol = wv & 1;
    const int quad = lane >> 4, l16 = lane & 15;
    const int m0 = blockIdx.y * 128, n0 = blockIdx.x * 128;

    // ---- stage addressing ----
    // per GLL call: 4 waves x 64 lanes x 16B = 64 rows x 64B.
    // wave wv covers rows wv*16 + (lane>>2); LDS unit = lane&3 (linear),
    // global unit fetched = (lane&3) ^ ((row>>1)&3) = (lane&3)^((lane>>3)&3).
    const int row64 = (wv << 4) + (lane >> 2);            // 0..63
    const int gu = (lane & 3) ^ ((lane >> 3) & 3);        // pre-swizzled unit
    const size_t aoff = (size_t)(m0 + row64) * K + gu * 8;
    const size_t boff = (size_t)(n0 + row64) * K + gu * 8;
    const int lch = wv * 512;                             // wave LDS chunk (shorts)

    f32x4 acc[4][4];
#pragma unroll
    for (int i = 0; i < 4; i++)
#pragma unroll
        for (int j = 0; j < 4; j++) acc[i][j] = (f32x4){0.f, 0.f, 0.f, 0.f};

    // prologue: stage K-step 0 into buffer 0
    GLL16(A  + aoff,                   &As[0][lch]);
    GLL16(A  + aoff + (size_t)64 * K,  &As[0][2048 + lch]);
    GLL16(Bt + boff,                   &Bs[0][lch]);
    GLL16(Bt + boff + (size_t)64 * K,  &Bs[0][2048 + lch]);

    // read-side unswizzle: (row>>1)&3 == (l16>>1)&3 (t*16, wrow*64 are ≡0 mod 4)
    const int swo = (quad ^ ((l16 >> 1) & 3)) * 8;        // shorts within row

    const int NK = K >> 5;
    for (int ks = 0; ks < NK; ks++) {
        asm volatile("s_waitcnt vmcnt(0)" ::: "memory");  // this step's DMA landed
        __syncthreads();
        if (ks + 1 < NK) {
            const int pn = (ks + 1) & 1;
            const int kc = (ks + 1) << 5;
            GLL16(A  + aoff + kc,                  &As[pn][lch]);
            GLL16(A  + aoff + (size_t)64 * K + kc, &As[pn][2048 + lch]);
            GLL16(Bt + boff + kc,                  &Bs[pn][lch]);
            GLL16(Bt + boff + (size_t)64 * K + kc, &Bs[pn][2048 + lch]);
        }
        const int pb = ks & 1;

        bf16x8 af[4], bfr[4];
#pragma unroll
        for (int t = 0; t < 4; t++)
            af[t] = *reinterpret_cast<bf16x8*>(&As[pb][(wrow * 64 + t * 16 + l16) * 32 + swo]);
#pragma unroll
        for (int t = 0; t < 4; t++)
            bfr[t] = *reinterpret_cast<bf16x8*>(&Bs[pb][(wcol * 64 + t * 16 + l16) * 32 + swo]);
#pragma unroll
        for (int rt = 0; rt < 4; rt++)
#pragma unroll
            for (int ct = 0; ct < 4; ct++)
                acc[rt][ct] = MFMA16(af[rt], bfr[ct], acc[rt][ct]);
    }

    // epilogue: C/D layout col=lane&15, row=quad*4+reg
#pragma unroll
    for (int rt = 0; rt < 4; rt++) {
#pragma unroll
        for (int ct = 0; ct < 4; ct++) {
            const int c = n0 + wcol * 64 + ct * 16 + l16;
#pragma unroll
            for (int reg = 0; reg < 4; reg++) {
                const int r = m0 + wrow * 64 + rt * 16 + quad * 4 + reg;
                const float v = acc[rt][ct][reg];
                if (MODE == 0) {
                    const int b = r >> 10, n = r & 1023;
                    const int which = (c >= 1536) ? 2 : (c >= 768 ? 1 : 0);
                    const int cc = c - which * 768;
                    const int h = cc >> 6, d = cc & 63;
                    const int bh = b * HH + h;
                    const short bv = f2bf(v);
                    if (which == 0)      qb[(bh << 16) + (n << 6) + d] = bv;
                    else if (which == 1) kb[(bh << 16) + (n << 6) + d] = bv;
                    else                 vtb[(bh << 16) + (d << 10) + n] = bv;
                } else {
                    outp[(size_t)r * 768 + c] = v + bias[c];
                }
            }
        }
    }
}

// ---------- attention pass 1 v5: gll + double-buffer + XOR swizzle ----------
// Block = (b, n128, m128): 512 blocks x 512 threads, 2 blocks/CU (64 KB LDS).
// Staging via global_load_lds (no VGPR round-trip, no ds_write cost),
// DOUBLE-buffered: head h+1's DMA is issued right after the single per-head
// barrier and lands during head h's full compute phase (m97 pipeline).
// Rows are 128 B unpadded (gll writes linearly) -> XOR-swizzle 16B units:
// global unit g stored at LDS unit g^(row&7); pre-swizzled on the global
// source side, un-swizzled on the ds_read side (both-sides-or-neither).
// b = bid&7 pins each batch's 3 MB Q+K slice in one XCD's L2.
__global__ __launch_bounds__(512, 4)
void attn_den5(const short* __restrict__ qb, const short* __restrict__ kb,
               short* __restrict__ invp) {
    __shared__ __align__(16) short Qs[2][128 * 64];
    __shared__ __align__(16) short Ks[2][128 * 64];

    const int tid = threadIdx.x, lane = tid & 63, wv = tid >> 6;  // wv 0..7
    const int wrow = wv >> 2, wcol = wv & 3;                      // 2 x 4
    const int quad = lane >> 4, l16 = lane & 15;
    const int bid = blockIdx.x;
    const int b = bid & 7;
    const int nmt = bid >> 3;            // 0..63
    const int n0 = (nmt >> 3) << 7;      // n128 base
    const int m0 = (nmt & 7) << 7;       // m128 base

    // ---- stage addressing (per-lane global, wave-uniform LDS) ----
    const int r8 = lane >> 3;                 // 0..7, == row&7
    const int gu = (lane & 7) ^ r8;           // pre-swizzled global unit
    const int qo0 = (n0 + wv * 8 + r8) * 64 + gu * 8;   // shorts
    const int qo1 = qo0 + 64 * 64;                      // +64 rows
    const int ko0 = (m0 + wv * 8 + r8) * 64 + gu * 8;
    const int ko1 = ko0 + 64 * 64;
    const int lc0 = wv * 512;                 // wave LDS chunk, it=0 (shorts)
    const int lc1 = 4096 + wv * 512;          // it=1

    f32x4 den[4][2];
#pragma unroll
    for (int i = 0; i < 4; i++)
#pragma unroll
        for (int j = 0; j < 2; j++) den[i][j] = (f32x4){0.f, 0.f, 0.f, 0.f};
    const f32x4 z = (f32x4){0.f, 0.f, 0.f, 0.f};

    // prologue: stage head 0 into buffer 0
    {
        const short* qh = qb + ((size_t)(b * HH) << 16);
        const short* kh = kb + ((size_t)(b * HH) << 16);
        GLL16(qh + qo0, &Qs[0][lc0]);
        GLL16(qh + qo1, &Qs[0][lc1]);
        GLL16(kh + ko0, &Ks[0][lc0]);
        GLL16(kh + ko1, &Ks[0][lc1]);
    }

    for (int h = 0; h < HH; h++) {
        asm volatile("s_waitcnt vmcnt(0)" ::: "memory");  // this head's DMA landed
        __syncthreads();                                  // all waves see it
        if (h < HH - 1) {  // issue next head's DMA into the other buffer
            const int pn = (h + 1) & 1;
            const short* qh = qb + ((size_t)(b * HH + h + 1) << 16);
            const short* kh = kb + ((size_t)(b * HH + h + 1) << 16);
            GLL16(qh + qo0, &Qs[pn][lc0]);
            GLL16(qh + qo1, &Qs[pn][lc1]);
            GLL16(kh + ko0, &Ks[pn][lc0]);
            GLL16(kh + ko1, &Ks[pn][lc1]);
        }
        const int pb = h & 1;
        const int sw0 = (quad ^ (l16 & 7)) * 8;   // swizzled unit, half 0 (shorts)

        bf16x8 aq[4][2], bk[2][2];
#pragma unroll
        for (int t = 0; t < 4; t++) {
            const int row = wrow * 64 + t * 16 + l16;
            aq[t][0] = *reinterpret_cast<bf16x8*>(&Qs[pb][row * 64 + sw0]);
            aq[t][1] = *reinterpret_cast<bf16x8*>(&Qs[pb][row * 64 + (sw0 ^ 32)]);
        }
#pragma unroll
        for (int t = 0; t < 2; t++) {
            const int row = wcol * 32 + t * 16 + l16;
            bk[t][0] = *reinterpret_cast<bf16x8*>(&Ks[pb][row * 64 + sw0]);
            bk[t][1] = *reinterpret_cast<bf16x8*>(&Ks[pb][row * 64 + (sw0 ^ 32)]);
        }
#pragma unroll
        for (int nt = 0; nt < 4; nt++)
#pragma unroll
            for (int mt = 0; mt < 2; mt++) {
                f32x4 s = MFMA16(aq[nt][0], bk[mt][0], z);
                s = MFMA16(aq[nt][1], bk[mt][1], s);
#pragma unroll
                for (int r = 0; r < 4; r++)
                    den[nt][mt][r] += __builtin_amdgcn_exp2f(s[r] * SCL2E);
            }
    }

    // write inv_den in raw (tile, lane, reg) C-layout (same as pass 2 reads)
#pragma unroll
    for (int nt = 0; nt < 4; nt++)
#pragma unroll
        for (int mt = 0; mt < 2; mt++) {
            const int ntg = (n0 >> 4) + wrow * 4 + nt;
            const int mtg = (m0 >> 4) + wcol * 2 + mt;
            ushort4 o;
            o.x = (unsigned short)f2bf(1.0f / den[nt][mt][0]);
            o.y = (unsigned short)f2bf(1.0f / den[nt][mt][1]);
            o.z = (unsigned short)f2bf(1.0f / den[nt][mt][2]);
            o.w = (unsigned short)f2bf(1.0f / den[nt][mt][3]);
            *reinterpret_cast<ushort4*>(&invp[(((b * 64 + ntg) * 64 + mtg) * 64 + lane) * 4]) = o;
        }
}

// ---------- attention pass 2 v2: per-head recompute-S + PV ----------
// Block = (b, h, n128): 768 blocks (3/CU), 4 waves, wave = 32 n-rows.
// K/V double-buffered in LDS -> ONE barrier per m32-iter. P transposed
// through wave-private LDS stash (intra-wave, no barrier).
__global__ __launch_bounds__(256, 4)
void attn_pv2(const short* __restrict__ qb, const short* __restrict__ kb,
              const short* __restrict__ vtb, const short* __restrict__ invp,
              short* __restrict__ attn_out) {
    __shared__ __align__(16) short Ks[2][32 * 72];   // [m][d]
    __shared__ __align__(16) short Vs[2][64 * 40];   // [d][m]
    __shared__ __align__(16) short Ps[4][32 * 40];   // per-wave [n][m]

    const int tid = threadIdx.x, lane = tid & 63, wv = tid >> 6;
    const int quad = lane >> 4, l16 = lane & 15;
    const int bid = blockIdx.x;
    const int b = bid & 7;
    const int r = bid >> 3;              // 0..95
    const int n4 = r / 12;               // 0..7 (n128 tile)
    const int h = r - n4 * 12;
    const int nb = n4 << 7;
    const int bh = b * HH + h;

    // Q A-frags for 2 n16-tiles
    bf16x8 aq[2][2];
#pragma unroll
    for (int nt = 0; nt < 2; nt++) {
        const short* qp = qb + (bh << 16) + ((nb + wv * 32 + nt * 16 + l16) << 6) + quad * 8;
        aq[nt][0] = *reinterpret_cast<const bf16x8*>(qp);
        aq[nt][1] = *reinterpret_cast<const bf16x8*>(qp + 32);
    }

    const f32x4 z = (f32x4){0.f, 0.f, 0.f, 0.f};
    f32x4 O[2][4];
#pragma unroll
    for (int nt = 0; nt < 2; nt++)
#pragma unroll
        for (int d = 0; d < 4; d++) O[nt][d] = z;

    const int krow = tid >> 3, koff = (tid & 7) * 8;   // K: 32 rows x 128B
    const int vrow = tid >> 2, voff = (tid & 3) * 8;   // V: 64 rows x 64B

    // preload tile 0
    uint4 kreg = *reinterpret_cast<const uint4*>(kb + (bh << 16) + (krow << 6) + koff);
    uint4 vreg = *reinterpret_cast<const uint4*>(vtb + (bh << 16) + (vrow << 10) + voff);

    for (int it = 0; it < 32; it++) {
        const int p = it & 1;
        *reinterpret_cast<uint4*>(&Ks[p][krow * 72 + koff]) = kreg;
        *reinterpret_cast<uint4*>(&Vs[p][vrow * 40 + voff]) = vreg;
        __syncthreads();
        if (it < 31) {
            const int m1 = (it + 1) << 5;
            kreg = *reinterpret_cast<const uint4*>(kb + (bh << 16) + ((m1 + krow) << 6) + koff);
            vreg = *reinterpret_cast<const uint4*>(vtb + (bh << 16) + (vrow << 10) + m1 + voff);
        }
        const int m0 = it << 5;

        // S + P-stash for two m16-halves x two n-tiles
#pragma unroll
        for (int mh = 0; mh < 2; mh++) {
            const bf16x8 k0 = *reinterpret_cast<bf16x8*>(&Ks[p][(mh * 16 + l16) * 72 + quad * 8]);
            const bf16x8 k1 = *reinterpret_cast<bf16x8*>(&Ks[p][(mh * 16 + l16) * 72 + quad * 8 + 32]);
            const int mt = (m0 >> 4) + mh;
#pragma unroll
            for (int nt = 0; nt < 2; nt++) {
                f32x4 s = MFMA16(aq[nt][0], k0, z);
                s = MFMA16(aq[nt][1], k1, s);
                const int ntg = (nb >> 4) + wv * 2 + nt;
                const ushort4 iv = *reinterpret_cast<const ushort4*>(
                    &invp[(((b * 64 + ntg) * 64 + mt) * 64 + lane) * 4]);
                Ps[wv][(nt * 16 + quad * 4 + 0) * 40 + mh * 16 + l16] = f2bf(__expf(s[0] * SCALE) * bf2f(iv.x));
                Ps[wv][(nt * 16 + quad * 4 + 1) * 40 + mh * 16 + l16] = f2bf(__expf(s[1] * SCALE) * bf2f(iv.y));
                Ps[wv][(nt * 16 + quad * 4 + 2) * 40 + mh * 16 + l16] = f2bf(__expf(s[2] * SCALE) * bf2f(iv.z));
                Ps[wv][(nt * 16 + quad * 4 + 3) * 40 + mh * 16 + l16] = f2bf(__expf(s[3] * SCALE) * bf2f(iv.w));
            }
        }
        __threadfence_block();  // intra-wave cross-lane RAW on Ps

        // PV
        bf16x8 pa[2];
#pragma unroll
        for (int nt = 0; nt < 2; nt++)
            pa[nt] = *reinterpret_cast<bf16x8*>(&Ps[wv][(nt * 16 + l16) * 40 + quad * 8]);
#pragma unroll
        for (int dch = 0; dch < 4; dch++) {
            const bf16x8 vf = *reinterpret_cast<bf16x8*>(&Vs[p][(dch * 16 + l16) * 40 + quad * 8]);
#pragma unroll
            for (int nt = 0; nt < 2; nt++)
                O[nt][dch] = MFMA16(pa[nt], vf, O[nt][dch]);
        }
    }

    // epilogue
#pragma unroll
    for (int nt = 0; nt < 2; nt++)
#pragma unroll
        for (int dch = 0; dch < 4; dch++) {
            const int col = h * 64 + dch * 16 + l16;
#pragma unroll
            for (int reg = 0; reg < 4; reg++) {
                const int n = nb + wv * 32 + nt * 16 + quad * 4 + reg;
                attn_out[(size_t)((b << 10) + n) * 768 + col] = f2bf(O[nt][dch][reg]);
            }
        }
}

// ---------- launch ----------
extern "C" void kernel_launch(void* const* d_in, const int* in_sizes, int n_in,
                              void* d_out, int out_size, void* d_ws, size_t ws_size,
                              hipStream_t stream) {
    const float* x     = (const float*)d_in[0];
    const float* w_qkv = (const float*)d_in[1];
    const float* w_out = (const float*)d_in[2];
    const float* b_out = (const float*)d_in[3];
    float* out = (float*)d_out;

    short* xb   = (short*)d_ws;                 // [8192][768]
    short* wT1  = xb  + 8192 * 768;             // [2304][768]
    short* wT2  = wT1 + 2304 * 768;             // [768][768]
    short* qb   = wT2 + 768 * 768;              // [b][h][n][d]
    short* kb   = qb  + 96 * 65536;
    short* vtb  = kb  + 96 * 65536;             // [b][h][d][n]
    short* attn = vtb + 96 * 65536;             // [8192][768]
    short* invp = attn + 8192 * 768;            // [b][nt][mt][lane][4]

    cast_to_bf16<<<6144, 256, 0, stream>>>(x, xb, (8192 * 768) / 4);
    transpose_cast<<<(2304 * 768) / 256, 256, 0, stream>>>(w_qkv, wT1, 768, 2304);
    transpose_cast<<<(768 * 768) / 256, 256, 0, stream>>>(w_out, wT2, 768, 768);

    gemm128<0><<<dim3(2304 / 128, 8192 / 128), 256, 0, stream>>>(
        xb, wT1, 768, qb, kb, vtb, nullptr, nullptr);

    attn_den5<<<512, 512, 0, stream>>>(qb, kb, invp);
    attn_pv2<<<768, 256, 0, stream>>>(qb, kb, vtb, invp, attn);

    gemm128<1><<<dim3(768 / 128, 8192 / 128), 256, 0, stream>>>(
        attn, wT2, 768, nullptr, nullptr, nullptr, out, b_out);
}

// Round 5
// 256.047 us; speedup vs baseline: 1.6288x; 1.0054x over previous
//
#include <hip/hip_runtime.h>

// ---------- common types ----------
typedef float  f32x4  __attribute__((ext_vector_type(4)));
typedef short  bf16x8 __attribute__((ext_vector_type(8)));

#define MFMA16(a, b, c) __builtin_amdgcn_mfma_f32_16x16x32_bf16((a), (b), (c), 0, 0, 0)

// global -> LDS direct DMA, 16B per lane. LDS dest is wave-uniform base +
// lane*16 (linear); global src is per-lane.
#define GLL16(g, l) __builtin_amdgcn_global_load_lds(                      \
    (const __attribute__((address_space(1))) void*)(g),                    \
    (__attribute__((address_space(3))) void*)(l), 16, 0, 0)

__device__ __forceinline__ short f2bf(float f) {
    union { float f; unsigned u; } a; a.f = f;
    unsigned r = a.u + 0x7fffu + ((a.u >> 16) & 1u);  // RNE
    return (short)(r >> 16);
}
__device__ __forceinline__ float bf2f(unsigned short u) {
    union { unsigned u; float f; } a; a.u = ((unsigned)u) << 16; return a.f;
}

// sizes
#define Bb   8
#define Nn   1024
#define DIM  768
#define HH   12
#define HD   64
#define INNER 768
#define SCALE 0.125f
// SCALE * log2(e): exp(s*SCALE) == exp2(s*SCL2E)
#define SCL2E 0.18033688011112042f

// ---------- prep kernels ----------
__global__ void cast_to_bf16(const float* __restrict__ in, short* __restrict__ out, int n4) {
    int i = blockIdx.x * 256 + threadIdx.x;
    if (i >= n4) return;
    float4 f = reinterpret_cast<const float4*>(in)[i];
    unsigned lo = (unsigned)(unsigned short)f2bf(f.x) | ((unsigned)(unsigned short)f2bf(f.y) << 16);
    unsigned hi = (unsigned)(unsigned short)f2bf(f.z) | ((unsigned)(unsigned short)f2bf(f.w) << 16);
    reinterpret_cast<uint2*>(out)[i] = make_uint2(lo, hi);
}

// wt[c][k] = w[k][c]; w is [rows=K][cols], wt is [cols][K]
__global__ void transpose_cast(const float* __restrict__ w, short* __restrict__ wt,
                               int rows, int cols) {
    int idx = blockIdx.x * 256 + threadIdx.x;
    if (idx >= rows * cols) return;
    int c = idx / rows;
    int k = idx - c * rows;
    wt[idx] = f2bf(w[k * cols + c]);
}

// ---------- GEMM v4: 3-buffer counted-vmcnt pipeline (T3+T4) ----------
// C[M,N] = A[M,K] @ Bt[N,K]^T. 128x128 tile, BK=32, 4 waves (2x2, 64x64 each).
// R4 lesson: __syncthreads() lowers to s_waitcnt vmcnt(0)+barrier -> every
// K-step fully drained the DMA queue (1-deep pipeline, latency exposed).
// Now: RAW s_barrier + counted vmcnt(4) (never 0 mid-loop), 3 LDS buffers,
// stage distance 2. Phase ks:
//   ds_read(buf[ks%3]) ; STAGE(ks+2 -> buf[(ks+2)%3])  [that buf was last
//   read at phase ks-1, protected by its trailing barrier] ; vmcnt(4)
//   [stage ks+1 landed] ; s_barrier [publish] ; lgkmcnt(0)+sched_barrier
//   [rule 18] ; 16 MFMA ; s_barrier [reads done -> overwrite ok next phase].
// 48 KB LDS -> 3 blocks/CU. XOR-swizzle unchanged from R4 (0 conflicts).
#define STAGE(ksv, bv)                                                      \
  { const int kc_ = (ksv) << 5;                                             \
    GLL16(A  + aoff + kc_,                  &As[bv][lch]);                  \
    GLL16(A  + aoff + (size_t)64 * K + kc_, &As[bv][2048 + lch]);           \
    GLL16(Bt + boff + kc_,                  &Bs[bv][lch]);                  \
    GLL16(Bt + boff + (size_t)64 * K + kc_, &Bs[bv][2048 + lch]); }

#define PHASE(VM, DO_STAGE)                                                 \
  {                                                                         \
    bf16x8 af[4], bfr[4];                                                   \
    _Pragma("unroll") for (int t = 0; t < 4; t++)                           \
      af[t] = *reinterpret_cast<const bf16x8*>(                             \
          &As[bi][(wrow * 64 + t * 16 + l16) * 32 + swo]);                  \
    _Pragma("unroll") for (int t = 0; t < 4; t++)                           \
      bfr[t] = *reinterpret_cast<const bf16x8*>(                            \
          &Bs[bi][(wcol * 64 + t * 16 + l16) * 32 + swo]);                  \
    if (DO_STAGE) { STAGE(ks + 2, bn); }                                    \
    asm volatile("s_waitcnt vmcnt(" #VM ")" ::: "memory");                  \
    __builtin_amdgcn_s_barrier();                                           \
    asm volatile("s_waitcnt lgkmcnt(0)" ::: "memory");                      \
    __builtin_amdgcn_sched_barrier(0);                                      \
    __builtin_amdgcn_s_setprio(1);                                          \
    _Pragma("unroll") for (int rt = 0; rt < 4; rt++)                        \
      _Pragma("unroll") for (int ct = 0; ct < 4; ct++)                      \
        acc[rt][ct] = MFMA16(af[rt], bfr[ct], acc[rt][ct]);                 \
    __builtin_amdgcn_s_setprio(0);                                          \
    __builtin_amdgcn_s_barrier();                                           \
  }

template <int MODE>
__global__ __launch_bounds__(256, 3)
void gemm128(const short* __restrict__ A, const short* __restrict__ Bt, int K,
             short* __restrict__ qb, short* __restrict__ kb, short* __restrict__ vtb,
             float* __restrict__ outp, const float* __restrict__ bias) {
    __shared__ __align__(16) short As[3][128 * 32];
    __shared__ __align__(16) short Bs[3][128 * 32];

    const int tid  = threadIdx.x;
    const int lane = tid & 63, wv = tid >> 6;
    const int wrow = wv >> 1, wcol = wv & 1;
    const int quad = lane >> 4, l16 = lane & 15;
    const int m0 = blockIdx.y * 128, n0 = blockIdx.x * 128;

    // ---- stage addressing ----
    // per GLL call: 4 waves x 64 lanes x 16B = 64 rows x 64B.
    // wave wv covers rows wv*16 + (lane>>2); LDS unit = lane&3 (linear),
    // global unit fetched = (lane&3) ^ ((row>>1)&3) = (lane&3)^((lane>>3)&3).
    const int row64 = (wv << 4) + (lane >> 2);            // 0..63
    const int gu = (lane & 3) ^ ((lane >> 3) & 3);        // pre-swizzled unit
    const size_t aoff = (size_t)(m0 + row64) * K + gu * 8;
    const size_t boff = (size_t)(n0 + row64) * K + gu * 8;
    const int lch = wv * 512;                             // wave LDS chunk (shorts)

    f32x4 acc[4][4];
#pragma unroll
    for (int i = 0; i < 4; i++)
#pragma unroll
        for (int j = 0; j < 4; j++) acc[i][j] = (f32x4){0.f, 0.f, 0.f, 0.f};

    // read-side unswizzle: (row>>1)&3 == (l16>>1)&3 (t*16, wrow*64 are ≡0 mod 4)
    const int swo = (quad ^ ((l16 >> 1) & 3)) * 8;        // shorts within row

    const int NK = K >> 5;  // 24

    // prologue: stage steps 0,1 into buffers 0,1; publish step 0
    STAGE(0, 0);
    STAGE(1, 1);
    asm volatile("s_waitcnt vmcnt(4)" ::: "memory");      // step 0 landed
    __builtin_amdgcn_s_barrier();

    int bi = 0, bn = 2;
    int ks = 0;
    for (; ks < NK - 2; ks++) {
        PHASE(4, true);
        bi = (bi == 2) ? 0 : bi + 1;
        bn = (bn == 2) ? 0 : bn + 1;
    }
    PHASE(0, false);                                      // ks == NK-2
    bi = (bi == 2) ? 0 : bi + 1;
    PHASE(0, false);                                      // ks == NK-1 (bi final)

    // epilogue: C/D layout col=lane&15, row=quad*4+reg
#pragma unroll
    for (int rt = 0; rt < 4; rt++) {
#pragma unroll
        for (int ct = 0; ct < 4; ct++) {
            const int c = n0 + wcol * 64 + ct * 16 + l16;
#pragma unroll
            for (int reg = 0; reg < 4; reg++) {
                const int r = m0 + wrow * 64 + rt * 16 + quad * 4 + reg;
                const float v = acc[rt][ct][reg];
                if (MODE == 0) {
                    const int b = r >> 10, n = r & 1023;
                    const int which = (c >= 1536) ? 2 : (c >= 768 ? 1 : 0);
                    const int cc = c - which * 768;
                    const int h = cc >> 6, d = cc & 63;
                    const int bh = b * HH + h;
                    const short bv = f2bf(v);
                    if (which == 0)      qb[(bh << 16) + (n << 6) + d] = bv;
                    else if (which == 1) kb[(bh << 16) + (n << 6) + d] = bv;
                    else                 vtb[(bh << 16) + (d << 10) + n] = bv;
                } else {
                    outp[(size_t)r * 768 + c] = v + bias[c];
                }
            }
        }
    }
}

// ---------- attention pass 1 v5: gll + double-buffer + XOR swizzle ----------
// Block = (b, n128, m128): 512 blocks x 512 threads, 2 blocks/CU (64 KB LDS).
// Staging via global_load_lds (no VGPR round-trip, no ds_write cost),
// DOUBLE-buffered: head h+1's DMA is issued right after the single per-head
// barrier and lands during head h's full compute phase (m97 pipeline).
// Rows are 128 B unpadded (gll writes linearly) -> XOR-swizzle 16B units:
// global unit g stored at LDS unit g^(row&7); pre-swizzled on the global
// source side, un-swizzled on the ds_read side (both-sides-or-neither).
// b = bid&7 pins each batch's 3 MB Q+K slice in one XCD's L2.
__global__ __launch_bounds__(512, 4)
void attn_den5(const short* __restrict__ qb, const short* __restrict__ kb,
               short* __restrict__ invp) {
    __shared__ __align__(16) short Qs[2][128 * 64];
    __shared__ __align__(16) short Ks[2][128 * 64];

    const int tid = threadIdx.x, lane = tid & 63, wv = tid >> 6;  // wv 0..7
    const int wrow = wv >> 2, wcol = wv & 3;                      // 2 x 4
    const int quad = lane >> 4, l16 = lane & 15;
    const int bid = blockIdx.x;
    const int b = bid & 7;
    const int nmt = bid >> 3;            // 0..63
    const int n0 = (nmt >> 3) << 7;      // n128 base
    const int m0 = (nmt & 7) << 7;       // m128 base

    // ---- stage addressing (per-lane global, wave-uniform LDS) ----
    const int r8 = lane >> 3;                 // 0..7, == row&7
    const int gu = (lane & 7) ^ r8;           // pre-swizzled global unit
    const int qo0 = (n0 + wv * 8 + r8) * 64 + gu * 8;   // shorts
    const int qo1 = qo0 + 64 * 64;                      // +64 rows
    const int ko0 = (m0 + wv * 8 + r8) * 64 + gu * 8;
    const int ko1 = ko0 + 64 * 64;
    const int lc0 = wv * 512;                 // wave LDS chunk, it=0 (shorts)
    const int lc1 = 4096 + wv * 512;          // it=1

    f32x4 den[4][2];
#pragma unroll
    for (int i = 0; i < 4; i++)
#pragma unroll
        for (int j = 0; j < 2; j++) den[i][j] = (f32x4){0.f, 0.f, 0.f, 0.f};
    const f32x4 z = (f32x4){0.f, 0.f, 0.f, 0.f};

    // prologue: stage head 0 into buffer 0
    {
        const short* qh = qb + ((size_t)(b * HH) << 16);
        const short* kh = kb + ((size_t)(b * HH) << 16);
        GLL16(qh + qo0, &Qs[0][lc0]);
        GLL16(qh + qo1, &Qs[0][lc1]);
        GLL16(kh + ko0, &Ks[0][lc0]);
        GLL16(kh + ko1, &Ks[0][lc1]);
    }

    for (int h = 0; h < HH; h++) {
        asm volatile("s_waitcnt vmcnt(0)" ::: "memory");  // this head's DMA landed
        __syncthreads();                                  // all waves see it
        if (h < HH - 1) {  // issue next head's DMA into the other buffer
            const int pn = (h + 1) & 1;
            const short* qh = qb + ((size_t)(b * HH + h + 1) << 16);
            const short* kh = kb + ((size_t)(b * HH + h + 1) << 16);
            GLL16(qh + qo0, &Qs[pn][lc0]);
            GLL16(qh + qo1, &Qs[pn][lc1]);
            GLL16(kh + ko0, &Ks[pn][lc0]);
            GLL16(kh + ko1, &Ks[pn][lc1]);
        }
        const int pb = h & 1;
        const int sw0 = (quad ^ (l16 & 7)) * 8;   // swizzled unit, half 0 (shorts)

        bf16x8 aq[4][2], bk[2][2];
#pragma unroll
        for (int t = 0; t < 4; t++) {
            const int row = wrow * 64 + t * 16 + l16;
            aq[t][0] = *reinterpret_cast<bf16x8*>(&Qs[pb][row * 64 + sw0]);
            aq[t][1] = *reinterpret_cast<bf16x8*>(&Qs[pb][row * 64 + (sw0 ^ 32)]);
        }
#pragma unroll
        for (int t = 0; t < 2; t++) {
            const int row = wcol * 32 + t * 16 + l16;
            bk[t][0] = *reinterpret_cast<bf16x8*>(&Ks[pb][row * 64 + sw0]);
            bk[t][1] = *reinterpret_cast<bf16x8*>(&Ks[pb][row * 64 + (sw0 ^ 32)]);
        }
#pragma unroll
        for (int nt = 0; nt < 4; nt++)
#pragma unroll
            for (int mt = 0; mt < 2; mt++) {
                f32x4 s = MFMA16(aq[nt][0], bk[mt][0], z);
                s = MFMA16(aq[nt][1], bk[mt][1], s);
#pragma unroll
                for (int r = 0; r < 4; r++)
                    den[nt][mt][r] += __builtin_amdgcn_exp2f(s[r] * SCL2E);
            }
    }

    // write inv_den in raw (tile, lane, reg) C-layout (same as pass 2 reads)
#pragma unroll
    for (int nt = 0; nt < 4; nt++)
#pragma unroll
        for (int mt = 0; mt < 2; mt++) {
            const int ntg = (n0 >> 4) + wrow * 4 + nt;
            const int mtg = (m0 >> 4) + wcol * 2 + mt;
            ushort4 o;
            o.x = (unsigned short)f2bf(1.0f / den[nt][mt][0]);
            o.y = (unsigned short)f2bf(1.0f / den[nt][mt][1]);
            o.z = (unsigned short)f2bf(1.0f / den[nt][mt][2]);
            o.w = (unsigned short)f2bf(1.0f / den[nt][mt][3]);
            *reinterpret_cast<ushort4*>(&invp[(((b * 64 + ntg) * 64 + mtg) * 64 + lane) * 4]) = o;
        }
}

// ---------- attention pass 2 v2: per-head recompute-S + PV ----------
// Block = (b, h, n128): 768 blocks (3/CU), 4 waves, wave = 32 n-rows.
// K/V double-buffered in LDS -> ONE barrier per m32-iter. P transposed
// through wave-private LDS stash (intra-wave, no barrier).
__global__ __launch_bounds__(256, 4)
void attn_pv2(const short* __restrict__ qb, const short* __restrict__ kb,
              const short* __restrict__ vtb, const short* __restrict__ invp,
              short* __restrict__ attn_out) {
    __shared__ __align__(16) short Ks[2][32 * 72];   // [m][d]
    __shared__ __align__(16) short Vs[2][64 * 40];   // [d][m]
    __shared__ __align__(16) short Ps[4][32 * 40];   // per-wave [n][m]

    const int tid = threadIdx.x, lane = tid & 63, wv = tid >> 6;
    const int quad = lane >> 4, l16 = lane & 15;
    const int bid = blockIdx.x;
    const int b = bid & 7;
    const int r = bid >> 3;              // 0..95
    const int n4 = r / 12;               // 0..7 (n128 tile)
    const int h = r - n4 * 12;
    const int nb = n4 << 7;
    const int bh = b * HH + h;

    // Q A-frags for 2 n16-tiles
    bf16x8 aq[2][2];
#pragma unroll
    for (int nt = 0; nt < 2; nt++) {
        const short* qp = qb + (bh << 16) + ((nb + wv * 32 + nt * 16 + l16) << 6) + quad * 8;
        aq[nt][0] = *reinterpret_cast<const bf16x8*>(qp);
        aq[nt][1] = *reinterpret_cast<const bf16x8*>(qp + 32);
    }

    const f32x4 z = (f32x4){0.f, 0.f, 0.f, 0.f};
    f32x4 O[2][4];
#pragma unroll
    for (int nt = 0; nt < 2; nt++)
#pragma unroll
        for (int d = 0; d < 4; d++) O[nt][d] = z;

    const int krow = tid >> 3, koff = (tid & 7) * 8;   // K: 32 rows x 128B
    const int vrow = tid >> 2, voff = (tid & 3) * 8;   // V: 64 rows x 64B

    // preload tile 0
    uint4 kreg = *reinterpret_cast<const uint4*>(kb + (bh << 16) + (krow << 6) + koff);
    uint4 vreg = *reinterpret_cast<const uint4*>(vtb + (bh << 16) + (vrow << 10) + voff);

    for (int it = 0; it < 32; it++) {
        const int p = it & 1;
        *reinterpret_cast<uint4*>(&Ks[p][krow * 72 + koff]) = kreg;
        *reinterpret_cast<uint4*>(&Vs[p][vrow * 40 + voff]) = vreg;
        __syncthreads();
        if (it < 31) {
            const int m1 = (it + 1) << 5;
            kreg = *reinterpret_cast<const uint4*>(kb + (bh << 16) + ((m1 + krow) << 6) + koff);
            vreg = *reinterpret_cast<const uint4*>(vtb + (bh << 16) + (vrow << 10) + m1 + voff);
        }
        const int m0 = it << 5;

        // S + P-stash for two m16-halves x two n-tiles
#pragma unroll
        for (int mh = 0; mh < 2; mh++) {
            const bf16x8 k0 = *reinterpret_cast<bf16x8*>(&Ks[p][(mh * 16 + l16) * 72 + quad * 8]);
            const bf16x8 k1 = *reinterpret_cast<bf16x8*>(&Ks[p][(mh * 16 + l16) * 72 + quad * 8 + 32]);
            const int mt = (m0 >> 4) + mh;
#pragma unroll
            for (int nt = 0; nt < 2; nt++) {
                f32x4 s = MFMA16(aq[nt][0], k0, z);
                s = MFMA16(aq[nt][1], k1, s);
                const int ntg = (nb >> 4) + wv * 2 + nt;
                const ushort4 iv = *reinterpret_cast<const ushort4*>(
                    &invp[(((b * 64 + ntg) * 64 + mt) * 64 + lane) * 4]);
                Ps[wv][(nt * 16 + quad * 4 + 0) * 40 + mh * 16 + l16] = f2bf(__expf(s[0] * SCALE) * bf2f(iv.x));
                Ps[wv][(nt * 16 + quad * 4 + 1) * 40 + mh * 16 + l16] = f2bf(__expf(s[1] * SCALE) * bf2f(iv.y));
                Ps[wv][(nt * 16 + quad * 4 + 2) * 40 + mh * 16 + l16] = f2bf(__expf(s[2] * SCALE) * bf2f(iv.z));
                Ps[wv][(nt * 16 + quad * 4 + 3) * 40 + mh * 16 + l16] = f2bf(__expf(s[3] * SCALE) * bf2f(iv.w));
            }
        }
        __threadfence_block();  // intra-wave cross-lane RAW on Ps

        // PV
        bf16x8 pa[2];
#pragma unroll
        for (int nt = 0; nt < 2; nt++)
            pa[nt] = *reinterpret_cast<bf16x8*>(&Ps[wv][(nt * 16 + l16) * 40 + quad * 8]);
#pragma unroll
        for (int dch = 0; dch < 4; dch++) {
            const bf16x8 vf = *reinterpret_cast<bf16x8*>(&Vs[p][(dch * 16 + l16) * 40 + quad * 8]);
#pragma unroll
            for (int nt = 0; nt < 2; nt++)
                O[nt][dch] = MFMA16(pa[nt], vf, O[nt][dch]);
        }
    }

    // epilogue
#pragma unroll
    for (int nt = 0; nt < 2; nt++)
#pragma unroll
        for (int dch = 0; dch < 4; dch++) {
            const int col = h * 64 + dch * 16 + l16;
#pragma unroll
            for (int reg = 0; reg < 4; reg++) {
                const int n = nb + wv * 32 + nt * 16 + quad * 4 + reg;
                attn_out[(size_t)((b << 10) + n) * 768 + col] = f2bf(O[nt][dch][reg]);
            }
        }
}

// ---------- launch ----------
extern "C" void kernel_launch(void* const* d_in, const int* in_sizes, int n_in,
                              void* d_out, int out_size, void* d_ws, size_t ws_size,
                              hipStream_t stream) {
    const float* x     = (const float*)d_in[0];
    const float* w_qkv = (const float*)d_in[1];
    const float* w_out = (const float*)d_in[2];
    const float* b_out = (const float*)d_in[3];
    float* out = (float*)d_out;

    short* xb   = (short*)d_ws;                 // [8192][768]
    short* wT1  = xb  + 8192 * 768;             // [2304][768]
    short* wT2  = wT1 + 2304 * 768;             // [768][768]
    short* qb   = wT2 + 768 * 768;              // [b][h][n][d]
    short* kb   = qb  + 96 * 65536;
    short* vtb  = kb  + 96 * 65536;             // [b][h][d][n]
    short* attn = vtb + 96 * 65536;             // [8192][768]
    short* invp = attn + 8192 * 768;            // [b][nt][mt][lane][4]

    cast_to_bf16<<<6144, 256, 0, stream>>>(x, xb, (8192 * 768) / 4);
    transpose_cast<<<(2304 * 768) / 256, 256, 0, stream>>>(w_qkv, wT1, 768, 2304);
    transpose_cast<<<(768 * 768) / 256, 256, 0, stream>>>(w_out, wT2, 768, 768);

    gemm128<0><<<dim3(2304 / 128, 8192 / 128), 256, 0, stream>>>(
        xb, wT1, 768, qb, kb, vtb, nullptr, nullptr);

    attn_den5<<<512, 512, 0, stream>>>(qb, kb, invp);
    attn_pv2<<<768, 256, 0, stream>>>(qb, kb, vtb, invp, attn);

    gemm128<1><<<dim3(768 / 128, 8192 / 128), 256, 0, stream>>>(
        attn, wT2, 768, nullptr, nullptr, nullptr, out, b_out);
}

// Round 6
// 234.720 us; speedup vs baseline: 1.7768x; 1.0909x over previous
//
#include <hip/hip_runtime.h>

// ---------- common types ----------
typedef float  f32x4  __attribute__((ext_vector_type(4)));
typedef short  bf16x8 __attribute__((ext_vector_type(8)));

#define MFMA16(a, b, c) __builtin_amdgcn_mfma_f32_16x16x32_bf16((a), (b), (c), 0, 0, 0)

// global -> LDS direct DMA, 16B per lane. LDS dest is wave-uniform base +
// lane*16 (linear); global src is per-lane.
#define GLL16(g, l) __builtin_amdgcn_global_load_lds(                      \
    (const __attribute__((address_space(1))) void*)(g),                    \
    (__attribute__((address_space(3))) void*)(l), 16, 0, 0)

__device__ __forceinline__ short f2bf(float f) {
    union { float f; unsigned u; } a; a.f = f;
    unsigned r = a.u + 0x7fffu + ((a.u >> 16) & 1u);  // RNE
    return (short)(r >> 16);
}
__device__ __forceinline__ float bf2f(unsigned short u) {
    union { unsigned u; float f; } a; a.u = ((unsigned)u) << 16; return a.f;
}

// sizes
#define Bb   8
#define Nn   1024
#define DIM  768
#define HH   12
#define HD   64
#define INNER 768
#define SCALE 0.125f
// SCALE * log2(e): exp(s*SCALE) == exp2(s*SCL2E)
#define SCL2E 0.18033688011112042f

// ---------- prep kernels ----------
__global__ void cast_to_bf16(const float* __restrict__ in, short* __restrict__ out, int n4) {
    int i = blockIdx.x * 256 + threadIdx.x;
    if (i >= n4) return;
    float4 f = reinterpret_cast<const float4*>(in)[i];
    unsigned lo = (unsigned)(unsigned short)f2bf(f.x) | ((unsigned)(unsigned short)f2bf(f.y) << 16);
    unsigned hi = (unsigned)(unsigned short)f2bf(f.z) | ((unsigned)(unsigned short)f2bf(f.w) << 16);
    reinterpret_cast<uint2*>(out)[i] = make_uint2(lo, hi);
}

// wt[c][k] = w[k][c]; w is [rows=K][cols], wt is [cols][K]
__global__ void transpose_cast(const float* __restrict__ w, short* __restrict__ wt,
                               int rows, int cols) {
    int idx = blockIdx.x * 256 + threadIdx.x;
    if (idx >= rows * cols) return;
    int c = idx / rows;
    int k = idx - c * rows;
    wt[idx] = f2bf(w[k * cols + c]);
}

// ---------- GEMM v5: 3-buffer counted-vmcnt pipeline + XCD swizzle ----------
// C[M,N] = A[M,K] @ Bt[N,K]^T. 128x128 tile, BK=32, 4 waves (2x2, 64x64 each).
// Sync schedule = R5 (proven): 3 LDS buffers, stage distance 2, counted
// vmcnt(4), raw s_barrier, lgkmcnt(0)+sched_barrier before MFMA (rule 18).
// NEW (R6): 1D grid + bijective XCD swizzle. Measured FETCH was 4x the
// one-pass ideal at 1.5 TB/s -> stage waits ate ~900cy HBM misses because
// panel-sharing blocks were scattered across the 8 per-XCD L2s. Decode
//   y = (bid&7)*8 + ((bid>>3)&7),  x = bid>>6
// puts 8 co-resident blocks per XCD on ONE B-panel (196KB) + an 8-row
// A-band (1.57MB) -> ~1.8MB L2 working set, stage hits L2 (~250cy),
// covered by the distance-2 prefetch.
#define STAGE(ksv, bv)                                                      \
  { const int kc_ = (ksv) << 5;                                             \
    GLL16(A  + aoff + kc_,                  &As[bv][lch]);                  \
    GLL16(A  + aoff + (size_t)64 * K + kc_, &As[bv][2048 + lch]);           \
    GLL16(Bt + boff + kc_,                  &Bs[bv][lch]);                  \
    GLL16(Bt + boff + (size_t)64 * K + kc_, &Bs[bv][2048 + lch]); }

#define PHASE(VM, DO_STAGE)                                                 \
  {                                                                         \
    bf16x8 af[4], bfr[4];                                                   \
    _Pragma("unroll") for (int t = 0; t < 4; t++)                           \
      af[t] = *reinterpret_cast<const bf16x8*>(                             \
          &As[bi][(wrow * 64 + t * 16 + l16) * 32 + swo]);                  \
    _Pragma("unroll") for (int t = 0; t < 4; t++)                           \
      bfr[t] = *reinterpret_cast<const bf16x8*>(                            \
          &Bs[bi][(wcol * 64 + t * 16 + l16) * 32 + swo]);                  \
    if (DO_STAGE) { STAGE(ks + 2, bn); }                                    \
    asm volatile("s_waitcnt vmcnt(" #VM ")" ::: "memory");                  \
    __builtin_amdgcn_s_barrier();                                           \
    asm volatile("s_waitcnt lgkmcnt(0)" ::: "memory");                      \
    __builtin_amdgcn_sched_barrier(0);                                      \
    __builtin_amdgcn_s_setprio(1);                                          \
    _Pragma("unroll") for (int rt = 0; rt < 4; rt++)                        \
      _Pragma("unroll") for (int ct = 0; ct < 4; ct++)                      \
        acc[rt][ct] = MFMA16(af[rt], bfr[ct], acc[rt][ct]);                 \
    __builtin_amdgcn_s_setprio(0);                                          \
    __builtin_amdgcn_s_barrier();                                           \
  }

template <int MODE>
__global__ __launch_bounds__(256, 3)
void gemm128(const short* __restrict__ A, const short* __restrict__ Bt, int K,
             short* __restrict__ qb, short* __restrict__ kb, short* __restrict__ vtb,
             float* __restrict__ outp, const float* __restrict__ bias) {
    __shared__ __align__(16) short As[3][128 * 32];
    __shared__ __align__(16) short Bs[3][128 * 32];

    const int tid  = threadIdx.x;
    const int lane = tid & 63, wv = tid >> 6;
    const int wrow = wv >> 1, wcol = wv & 1;
    const int quad = lane >> 4, l16 = lane & 15;

    // XCD-aware decode: 64 consecutive bids = one B-panel column across all
    // 8 XCDs; within an XCD, 8 blocks share that B-panel + an 8-row A-band.
    const int bid = blockIdx.x;
    const int m0 = (((bid & 7) << 3) | ((bid >> 3) & 7)) << 7;
    const int n0 = (bid >> 6) << 7;

    // ---- stage addressing ----
    // per GLL call: 4 waves x 64 lanes x 16B = 64 rows x 64B.
    // wave wv covers rows wv*16 + (lane>>2); LDS unit = lane&3 (linear),
    // global unit fetched = (lane&3) ^ ((row>>1)&3) = (lane&3)^((lane>>3)&3).
    const int row64 = (wv << 4) + (lane >> 2);            // 0..63
    const int gu = (lane & 3) ^ ((lane >> 3) & 3);        // pre-swizzled unit
    const size_t aoff = (size_t)(m0 + row64) * K + gu * 8;
    const size_t boff = (size_t)(n0 + row64) * K + gu * 8;
    const int lch = wv * 512;                             // wave LDS chunk (shorts)

    f32x4 acc[4][4];
#pragma unroll
    for (int i = 0; i < 4; i++)
#pragma unroll
        for (int j = 0; j < 4; j++) acc[i][j] = (f32x4){0.f, 0.f, 0.f, 0.f};

    // read-side unswizzle: (row>>1)&3 == (l16>>1)&3 (t*16, wrow*64 are ≡0 mod 4)
    const int swo = (quad ^ ((l16 >> 1) & 3)) * 8;        // shorts within row

    const int NK = K >> 5;  // 24

    // prologue: stage steps 0,1 into buffers 0,1; publish step 0
    STAGE(0, 0);
    STAGE(1, 1);
    asm volatile("s_waitcnt vmcnt(4)" ::: "memory");      // step 0 landed
    __builtin_amdgcn_s_barrier();

    int bi = 0, bn = 2;
    int ks = 0;
    for (; ks < NK - 2; ks++) {
        PHASE(4, true);
        bi = (bi == 2) ? 0 : bi + 1;
        bn = (bn == 2) ? 0 : bn + 1;
    }
    PHASE(0, false);                                      // ks == NK-2
    bi = (bi == 2) ? 0 : bi + 1;
    PHASE(0, false);                                      // ks == NK-1 (bi final)

    // epilogue: C/D layout col=lane&15, row=quad*4+reg
#pragma unroll
    for (int rt = 0; rt < 4; rt++) {
#pragma unroll
        for (int ct = 0; ct < 4; ct++) {
            const int c = n0 + wcol * 64 + ct * 16 + l16;
#pragma unroll
            for (int reg = 0; reg < 4; reg++) {
                const int r = m0 + wrow * 64 + rt * 16 + quad * 4 + reg;
                const float v = acc[rt][ct][reg];
                if (MODE == 0) {
                    const int b = r >> 10, n = r & 1023;
                    const int which = (c >= 1536) ? 2 : (c >= 768 ? 1 : 0);
                    const int cc = c - which * 768;
                    const int h = cc >> 6, d = cc & 63;
                    const int bh = b * HH + h;
                    const short bv = f2bf(v);
                    if (which == 0)      qb[(bh << 16) + (n << 6) + d] = bv;
                    else if (which == 1) kb[(bh << 16) + (n << 6) + d] = bv;
                    else                 vtb[(bh << 16) + (d << 10) + n] = bv;
                } else {
                    outp[(size_t)r * 768 + c] = v + bias[c];
                }
            }
        }
    }
}

// ---------- attention pass 1 v5: gll + double-buffer + XOR swizzle ----------
// Block = (b, n128, m128): 512 blocks x 512 threads, 2 blocks/CU (64 KB LDS).
// Staging via global_load_lds (no VGPR round-trip, no ds_write cost),
// DOUBLE-buffered: head h+1's DMA is issued right after the single per-head
// barrier and lands during head h's full compute phase (m97 pipeline).
// Rows are 128 B unpadded (gll writes linearly) -> XOR-swizzle 16B units:
// global unit g stored at LDS unit g^(row&7); pre-swizzled on the global
// source side, un-swizzled on the ds_read side (both-sides-or-neither).
// b = bid&7 pins each batch's 3 MB Q+K slice in one XCD's L2.
__global__ __launch_bounds__(512, 4)
void attn_den5(const short* __restrict__ qb, const short* __restrict__ kb,
               short* __restrict__ invp) {
    __shared__ __align__(16) short Qs[2][128 * 64];
    __shared__ __align__(16) short Ks[2][128 * 64];

    const int tid = threadIdx.x, lane = tid & 63, wv = tid >> 6;  // wv 0..7
    const int wrow = wv >> 2, wcol = wv & 3;                      // 2 x 4
    const int quad = lane >> 4, l16 = lane & 15;
    const int bid = blockIdx.x;
    const int b = bid & 7;
    const int nmt = bid >> 3;            // 0..63
    const int n0 = (nmt >> 3) << 7;      // n128 base
    const int m0 = (nmt & 7) << 7;       // m128 base

    // ---- stage addressing (per-lane global, wave-uniform LDS) ----
    const int r8 = lane >> 3;                 // 0..7, == row&7
    const int gu = (lane & 7) ^ r8;           // pre-swizzled global unit
    const int qo0 = (n0 + wv * 8 + r8) * 64 + gu * 8;   // shorts
    const int qo1 = qo0 + 64 * 64;                      // +64 rows
    const int ko0 = (m0 + wv * 8 + r8) * 64 + gu * 8;
    const int ko1 = ko0 + 64 * 64;
    const int lc0 = wv * 512;                 // wave LDS chunk, it=0 (shorts)
    const int lc1 = 4096 + wv * 512;          // it=1

    f32x4 den[4][2];
#pragma unroll
    for (int i = 0; i < 4; i++)
#pragma unroll
        for (int j = 0; j < 2; j++) den[i][j] = (f32x4){0.f, 0.f, 0.f, 0.f};
    const f32x4 z = (f32x4){0.f, 0.f, 0.f, 0.f};

    // prologue: stage head 0 into buffer 0
    {
        const short* qh = qb + ((size_t)(b * HH) << 16);
        const short* kh = kb + ((size_t)(b * HH) << 16);
        GLL16(qh + qo0, &Qs[0][lc0]);
        GLL16(qh + qo1, &Qs[0][lc1]);
        GLL16(kh + ko0, &Ks[0][lc0]);
        GLL16(kh + ko1, &Ks[0][lc1]);
    }

    for (int h = 0; h < HH; h++) {
        asm volatile("s_waitcnt vmcnt(0)" ::: "memory");  // this head's DMA landed
        __syncthreads();                                  // all waves see it
        if (h < HH - 1) {  // issue next head's DMA into the other buffer
            const int pn = (h + 1) & 1;
            const short* qh = qb + ((size_t)(b * HH + h + 1) << 16);
            const short* kh = kb + ((size_t)(b * HH + h + 1) << 16);
            GLL16(qh + qo0, &Qs[pn][lc0]);
            GLL16(qh + qo1, &Qs[pn][lc1]);
            GLL16(kh + ko0, &Ks[pn][lc0]);
            GLL16(kh + ko1, &Ks[pn][lc1]);
        }
        const int pb = h & 1;
        const int sw0 = (quad ^ (l16 & 7)) * 8;   // swizzled unit, half 0 (shorts)

        bf16x8 aq[4][2], bk[2][2];
#pragma unroll
        for (int t = 0; t < 4; t++) {
            const int row = wrow * 64 + t * 16 + l16;
            aq[t][0] = *reinterpret_cast<bf16x8*>(&Qs[pb][row * 64 + sw0]);
            aq[t][1] = *reinterpret_cast<bf16x8*>(&Qs[pb][row * 64 + (sw0 ^ 32)]);
        }
#pragma unroll
        for (int t = 0; t < 2; t++) {
            const int row = wcol * 32 + t * 16 + l16;
            bk[t][0] = *reinterpret_cast<bf16x8*>(&Ks[pb][row * 64 + sw0]);
            bk[t][1] = *reinterpret_cast<bf16x8*>(&Ks[pb][row * 64 + (sw0 ^ 32)]);
        }
#pragma unroll
        for (int nt = 0; nt < 4; nt++)
#pragma unroll
            for (int mt = 0; mt < 2; mt++) {
                f32x4 s = MFMA16(aq[nt][0], bk[mt][0], z);
                s = MFMA16(aq[nt][1], bk[mt][1], s);
#pragma unroll
                for (int r = 0; r < 4; r++)
                    den[nt][mt][r] += __builtin_amdgcn_exp2f(s[r] * SCL2E);
            }
    }

    // write inv_den in raw (tile, lane, reg) C-layout (same as pass 2 reads)
#pragma unroll
    for (int nt = 0; nt < 4; nt++)
#pragma unroll
        for (int mt = 0; mt < 2; mt++) {
            const int ntg = (n0 >> 4) + wrow * 4 + nt;
            const int mtg = (m0 >> 4) + wcol * 2 + mt;
            ushort4 o;
            o.x = (unsigned short)f2bf(1.0f / den[nt][mt][0]);
            o.y = (unsigned short)f2bf(1.0f / den[nt][mt][1]);
            o.z = (unsigned short)f2bf(1.0f / den[nt][mt][2]);
            o.w = (unsigned short)f2bf(1.0f / den[nt][mt][3]);
            *reinterpret_cast<ushort4*>(&invp[(((b * 64 + ntg) * 64 + mtg) * 64 + lane) * 4]) = o;
        }
}

// ---------- attention pass 2 v2: per-head recompute-S + PV ----------
// Block = (b, h, n128): 768 blocks (3/CU), 4 waves, wave = 32 n-rows.
// K/V double-buffered in LDS -> ONE barrier per m32-iter. P transposed
// through wave-private LDS stash (intra-wave, no barrier).
__global__ __launch_bounds__(256, 4)
void attn_pv2(const short* __restrict__ qb, const short* __restrict__ kb,
              const short* __restrict__ vtb, const short* __restrict__ invp,
              short* __restrict__ attn_out) {
    __shared__ __align__(16) short Ks[2][32 * 72];   // [m][d]
    __shared__ __align__(16) short Vs[2][64 * 40];   // [d][m]
    __shared__ __align__(16) short Ps[4][32 * 40];   // per-wave [n][m]

    const int tid = threadIdx.x, lane = tid & 63, wv = tid >> 6;
    const int quad = lane >> 4, l16 = lane & 15;
    const int bid = blockIdx.x;
    const int b = bid & 7;
    const int r = bid >> 3;              // 0..95
    const int n4 = r / 12;               // 0..7 (n128 tile)
    const int h = r - n4 * 12;
    const int nb = n4 << 7;
    const int bh = b * HH + h;

    // Q A-frags for 2 n16-tiles
    bf16x8 aq[2][2];
#pragma unroll
    for (int nt = 0; nt < 2; nt++) {
        const short* qp = qb + (bh << 16) + ((nb + wv * 32 + nt * 16 + l16) << 6) + quad * 8;
        aq[nt][0] = *reinterpret_cast<const bf16x8*>(qp);
        aq[nt][1] = *reinterpret_cast<const bf16x8*>(qp + 32);
    }

    const f32x4 z = (f32x4){0.f, 0.f, 0.f, 0.f};
    f32x4 O[2][4];
#pragma unroll
    for (int nt = 0; nt < 2; nt++)
#pragma unroll
        for (int d = 0; d < 4; d++) O[nt][d] = z;

    const int krow = tid >> 3, koff = (tid & 7) * 8;   // K: 32 rows x 128B
    const int vrow = tid >> 2, voff = (tid & 3) * 8;   // V: 64 rows x 64B

    // preload tile 0
    uint4 kreg = *reinterpret_cast<const uint4*>(kb + (bh << 16) + (krow << 6) + koff);
    uint4 vreg = *reinterpret_cast<const uint4*>(vtb + (bh << 16) + (vrow << 10) + voff);

    for (int it = 0; it < 32; it++) {
        const int p = it & 1;
        *reinterpret_cast<uint4*>(&Ks[p][krow * 72 + koff]) = kreg;
        *reinterpret_cast<uint4*>(&Vs[p][vrow * 40 + voff]) = vreg;
        __syncthreads();
        if (it < 31) {
            const int m1 = (it + 1) << 5;
            kreg = *reinterpret_cast<const uint4*>(kb + (bh << 16) + ((m1 + krow) << 6) + koff);
            vreg = *reinterpret_cast<const uint4*>(vtb + (bh << 16) + (vrow << 10) + m1 + voff);
        }
        const int m0 = it << 5;

        // S + P-stash for two m16-halves x two n-tiles
#pragma unroll
        for (int mh = 0; mh < 2; mh++) {
            const bf16x8 k0 = *reinterpret_cast<bf16x8*>(&Ks[p][(mh * 16 + l16) * 72 + quad * 8]);
            const bf16x8 k1 = *reinterpret_cast<bf16x8*>(&Ks[p][(mh * 16 + l16) * 72 + quad * 8 + 32]);
            const int mt = (m0 >> 4) + mh;
#pragma unroll
            for (int nt = 0; nt < 2; nt++) {
                f32x4 s = MFMA16(aq[nt][0], k0, z);
                s = MFMA16(aq[nt][1], k1, s);
                const int ntg = (nb >> 4) + wv * 2 + nt;
                const ushort4 iv = *reinterpret_cast<const ushort4*>(
                    &invp[(((b * 64 + ntg) * 64 + mt) * 64 + lane) * 4]);
                Ps[wv][(nt * 16 + quad * 4 + 0) * 40 + mh * 16 + l16] = f2bf(__expf(s[0] * SCALE) * bf2f(iv.x));
                Ps[wv][(nt * 16 + quad * 4 + 1) * 40 + mh * 16 + l16] = f2bf(__expf(s[1] * SCALE) * bf2f(iv.y));
                Ps[wv][(nt * 16 + quad * 4 + 2) * 40 + mh * 16 + l16] = f2bf(__expf(s[2] * SCALE) * bf2f(iv.z));
                Ps[wv][(nt * 16 + quad * 4 + 3) * 40 + mh * 16 + l16] = f2bf(__expf(s[3] * SCALE) * bf2f(iv.w));
            }
        }
        __threadfence_block();  // intra-wave cross-lane RAW on Ps

        // PV
        bf16x8 pa[2];
#pragma unroll
        for (int nt = 0; nt < 2; nt++)
            pa[nt] = *reinterpret_cast<bf16x8*>(&Ps[wv][(nt * 16 + l16) * 40 + quad * 8]);
#pragma unroll
        for (int dch = 0; dch < 4; dch++) {
            const bf16x8 vf = *reinterpret_cast<bf16x8*>(&Vs[p][(dch * 16 + l16) * 40 + quad * 8]);
#pragma unroll
            for (int nt = 0; nt < 2; nt++)
                O[nt][dch] = MFMA16(pa[nt], vf, O[nt][dch]);
        }
    }

    // epilogue
#pragma unroll
    for (int nt = 0; nt < 2; nt++)
#pragma unroll
        for (int dch = 0; dch < 4; dch++) {
            const int col = h * 64 + dch * 16 + l16;
#pragma unroll
            for (int reg = 0; reg < 4; reg++) {
                const int n = nb + wv * 32 + nt * 16 + quad * 4 + reg;
                attn_out[(size_t)((b << 10) + n) * 768 + col] = f2bf(O[nt][dch][reg]);
            }
        }
}

// ---------- launch ----------
extern "C" void kernel_launch(void* const* d_in, const int* in_sizes, int n_in,
                              void* d_out, int out_size, void* d_ws, size_t ws_size,
                              hipStream_t stream) {
    const float* x     = (const float*)d_in[0];
    const float* w_qkv = (const float*)d_in[1];
    const float* w_out = (const float*)d_in[2];
    const float* b_out = (const float*)d_in[3];
    float* out = (float*)d_out;

    short* xb   = (short*)d_ws;                 // [8192][768]
    short* wT1  = xb  + 8192 * 768;             // [2304][768]
    short* wT2  = wT1 + 2304 * 768;             // [768][768]
    short* qb   = wT2 + 768 * 768;              // [b][h][n][d]
    short* kb   = qb  + 96 * 65536;
    short* vtb  = kb  + 96 * 65536;             // [b][h][d][n]
    short* attn = vtb + 96 * 65536;             // [8192][768]
    short* invp = attn + 8192 * 768;            // [b][nt][mt][lane][4]

    cast_to_bf16<<<6144, 256, 0, stream>>>(x, xb, (8192 * 768) / 4);
    transpose_cast<<<(2304 * 768) / 256, 256, 0, stream>>>(w_qkv, wT1, 768, 2304);
    transpose_cast<<<(768 * 768) / 256, 256, 0, stream>>>(w_out, wT2, 768, 768);

    // 1D grids, XCD-swizzled decode inside the kernel.
    gemm128<0><<<1152, 256, 0, stream>>>(
        xb, wT1, 768, qb, kb, vtb, nullptr, nullptr);

    attn_den5<<<512, 512, 0, stream>>>(qb, kb, invp);
    attn_pv2<<<768, 256, 0, stream>>>(qb, kb, vtb, invp, attn);

    gemm128<1><<<384, 256, 0, stream>>>(
        attn, wT2, 768, nullptr, nullptr, nullptr, out, b_out);
}